// Round 1
// baseline (4995.940 us; speedup 1.0000x reference)
//
#include <hip/hip_runtime.h>
#include <hip/hip_bf16.h>
#include <math.h>

// Problem constants (match reference)
#define NHH 16
#define SS  2048
#define BBATCH 2
#define TT  4096            // B*S tokens
#define DQK 192             // D_NOPE + D_ROPE
#define QSCALE 0.07216878364870322f   // 1/sqrt(192)
#define ROPE_C 0.28782313662425574f   // 2*ln(10000)/64

__device__ __forceinline__ void rope_pair(float ce, float co, int fi, int spos,
                                          float& oe, float& oo) {
    // angle = pos * theta^(-2*fi/64)
    float freq = expf(-ROPE_C * (float)fi);
    float ang  = (float)spos * freq;
    float s = sinf(ang), c = cosf(ang);
    oe = ce * c - co * s;
    oo = ce * s + co * c;
}

// ---------------------------------------------------------------------------
// Generic fp32 NT GEMM: C[m][n] = sum_k A[m*K+k] * W[n*K+k]
// Tiles: BM=64, BN=64, BK=16; 256 threads; 4x4 register blocking.
// MODE epilogues:
//  0: plain C[m*N+n]
//  1: q_nope scatter (scaled): q[m*3072 + (n>>7)*192 + (n&127)]
//  2: q_rope (rope + scale):   q[m*3072 + (n>>6)*192 + 128 + (n&63)]
//  3: kv_up split: n>>8 = head, (n&255)<128 -> k_nope, else -> v
//  4: k_rope (rope, no scale): C[m*64 + n]
// ---------------------------------------------------------------------------
template<int MODE>
__global__ __launch_bounds__(256) void gemm_nt(
        const float* __restrict__ A, const float* __restrict__ W,
        float* __restrict__ C, float* __restrict__ C2,
        int M, int N, int K) {
    __shared__ float As[16][68];
    __shared__ float Bs[16][68];
    const int tid = threadIdx.x;
    const int tx = tid & 15;        // col group 0..15
    const int ty = tid >> 4;        // row group 0..15
    const int m0 = blockIdx.y * 64;
    const int n0 = blockIdx.x * 64;

    float acc[4][4];
#pragma unroll
    for (int i = 0; i < 4; ++i)
#pragma unroll
        for (int j = 0; j < 4; ++j) acc[i][j] = 0.f;

    const int lm = tid >> 2;          // 0..63 tile row
    const int lk = (tid & 3) << 2;    // 0,4,8,12
    const float* Aptr = A + (size_t)(m0 + lm) * K + lk;
    const float* Bptr = W + (size_t)(n0 + lm) * K + lk;

    for (int k0 = 0; k0 < K; k0 += 16) {
        const float4 av = *(const float4*)(Aptr + k0);
        const float4 bv = *(const float4*)(Bptr + k0);
        __syncthreads();
        As[lk + 0][lm] = av.x; As[lk + 1][lm] = av.y;
        As[lk + 2][lm] = av.z; As[lk + 3][lm] = av.w;
        Bs[lk + 0][lm] = bv.x; Bs[lk + 1][lm] = bv.y;
        Bs[lk + 2][lm] = bv.z; Bs[lk + 3][lm] = bv.w;
        __syncthreads();
#pragma unroll
        for (int kk = 0; kk < 16; ++kk) {
            const float4 a4 = *(const float4*)&As[kk][ty << 2];
            const float4 b4 = *(const float4*)&Bs[kk][tx << 2];
            const float a[4] = {a4.x, a4.y, a4.z, a4.w};
            const float b[4] = {b4.x, b4.y, b4.z, b4.w};
#pragma unroll
            for (int i = 0; i < 4; ++i)
#pragma unroll
                for (int j = 0; j < 4; ++j)
                    acc[i][j] = fmaf(a[i], b[j], acc[i][j]);
        }
    }

#pragma unroll
    for (int i = 0; i < 4; ++i) {
        const int m = m0 + (ty << 2) + i;
        if (MODE == 0) {
            float4 v = make_float4(acc[i][0], acc[i][1], acc[i][2], acc[i][3]);
            *(float4*)&C[(size_t)m * N + n0 + (tx << 2)] = v;
        } else if (MODE == 1) {
#pragma unroll
            for (int j = 0; j < 4; ++j) {
                const int n = n0 + (tx << 2) + j;
                C[(size_t)m * 3072 + (n >> 7) * 192 + (n & 127)] = acc[i][j] * QSCALE;
            }
        } else if (MODE == 2) {
            const int spos = m & (SS - 1);
#pragma unroll
            for (int j = 0; j < 4; j += 2) {
                const int ne = n0 + (tx << 2) + j;     // even column
                const int fi = (ne & 63) >> 1;
                float oe, oo;
                rope_pair(acc[i][j], acc[i][j + 1], fi, spos, oe, oo);
                float* dst = C + (size_t)m * 3072 + (ne >> 6) * 192 + 128 + (ne & 63);
                dst[0] = oe * QSCALE;
                dst[1] = oo * QSCALE;
            }
        } else if (MODE == 3) {
#pragma unroll
            for (int j = 0; j < 4; ++j) {
                const int n = n0 + (tx << 2) + j;
                const int h = n >> 8, off = n & 255;
                if (off < 128) C [(size_t)m * 2048 + h * 128 + off]         = acc[i][j];
                else           C2[(size_t)m * 2048 + h * 128 + (off - 128)] = acc[i][j];
            }
        } else if (MODE == 4) {
            const int spos = m & (SS - 1);
#pragma unroll
            for (int j = 0; j < 4; j += 2) {
                const int ne = n0 + (tx << 2) + j;
                const int fi = ne >> 1;
                float oe, oo;
                rope_pair(acc[i][j], acc[i][j + 1], fi, spos, oe, oo);
                C[(size_t)m * 64 + ne]     = oe;
                C[(size_t)m * 64 + ne + 1] = oo;
            }
        }
    }
}

// ---------------------------------------------------------------------------
// RMSNorm (in place): x[row] *= rsqrt(mean(x^2)+eps) * w
// ---------------------------------------------------------------------------
__global__ __launch_bounds__(256) void rmsnorm_k(float* __restrict__ x,
                                                 const float* __restrict__ w,
                                                 int N) {
    const int row = blockIdx.x;
    float* xr = x + (size_t)row * N;
    float ss = 0.f;
    for (int i = threadIdx.x; i < N; i += 256) {
        float v = xr[i];
        ss += v * v;
    }
    __shared__ float red[256];
    red[threadIdx.x] = ss;
    __syncthreads();
    for (int s = 128; s > 0; s >>= 1) {
        if (threadIdx.x < s) red[threadIdx.x] += red[threadIdx.x + s];
        __syncthreads();
    }
    const float scale = rsqrtf(red[0] / (float)N + 1e-6f);
    for (int i = threadIdx.x; i < N; i += 256) xr[i] = xr[i] * scale * w[i];
}

// ---------------------------------------------------------------------------
// Causal flash attention, fp32.
// Block: 256 threads = 16 q-rows x 16 col-groups, one (b,h,qtile16).
// K tiles of 32. q already scaled by 1/sqrt(192).
// q: [t][h][192], k_nope: [t][h*128+d], k_rope: [t][64], v: [t][h*128+d]
// att out: [t][h*128+c]
// ---------------------------------------------------------------------------
__global__ __launch_bounds__(256) void attn_k(
        const float* __restrict__ q, const float* __restrict__ knope,
        const float* __restrict__ krope, const float* __restrict__ vv,
        float* __restrict__ att) {
    const int qt = blockIdx.x;   // 0..127
    const int h  = blockIdx.y;   // 0..15
    const int b  = blockIdx.z;   // 0..1
    const int tid = threadIdx.x;
    const int r = tid >> 4;      // q row in tile 0..15
    const int g = tid & 15;      // col group 0..15

    __shared__ float Qs[16][196];
    __shared__ float Ks[32][196];
    __shared__ float Vs[32][132];
    __shared__ float Ps[16][33];

    const int q_row0 = qt * 16;
    for (int idx = tid; idx < 16 * 192; idx += 256) {
        const int rr = idx / 192, d = idx - rr * 192;
        Qs[rr][d] = q[((size_t)(b * SS + q_row0 + rr) * NHH + h) * DQK + d];
    }

    float O[8];
#pragma unroll
    for (int e = 0; e < 8; ++e) O[e] = 0.f;
    float m_old = -INFINITY, l = 0.f;

    const int nkt = (qt >> 1) + 1;
    for (int kt = 0; kt < nkt; ++kt) {
        __syncthreads();
        for (int idx = tid; idx < 32 * 192; idx += 256) {
            const int j = idx / 192, d = idx - j * 192;
            const int t = b * SS + kt * 32 + j;
            Ks[j][d] = (d < 128) ? knope[((size_t)t * NHH + h) * 128 + d]
                                 : krope[(size_t)t * 64 + (d - 128)];
        }
        for (int idx = tid; idx < 32 * 128; idx += 256) {
            const int j = idx >> 7, d = idx & 127;
            const int t = b * SS + kt * 32 + j;
            Vs[j][d] = vv[((size_t)t * NHH + h) * 128 + d];
        }
        __syncthreads();

        // scores for k columns j = g and j = g+16
        float s0 = 0.f, s1 = 0.f;
#pragma unroll 8
        for (int d = 0; d < 192; d += 4) {
            const float4 q4 = *(const float4*)&Qs[r][d];
            const float4 ka = *(const float4*)&Ks[g][d];
            const float4 kb = *(const float4*)&Ks[g + 16][d];
            s0 += q4.x * ka.x + q4.y * ka.y + q4.z * ka.z + q4.w * ka.w;
            s1 += q4.x * kb.x + q4.y * kb.y + q4.z * kb.z + q4.w * kb.w;
        }
        const int qglob = q_row0 + r;
        const int k0g = kt * 32;
        if (k0g + g      > qglob) s0 = -INFINITY;
        if (k0g + g + 16 > qglob) s1 = -INFINITY;

        float mt = fmaxf(s0, s1);
#pragma unroll
        for (int off = 1; off < 16; off <<= 1)
            mt = fmaxf(mt, __shfl_xor(mt, off));
        const float m_new = fmaxf(m_old, mt);
        const float alpha = expf(m_old - m_new);
        const float p0 = expf(s0 - m_new);
        const float p1 = expf(s1 - m_new);
        float lt = p0 + p1;
#pragma unroll
        for (int off = 1; off < 16; off <<= 1)
            lt += __shfl_xor(lt, off);
        l = l * alpha + lt;
        Ps[r][g] = p0;
        Ps[r][g + 16] = p1;
#pragma unroll
        for (int e = 0; e < 8; ++e) O[e] *= alpha;
        __syncthreads();

        const int c0 = g * 8;
#pragma unroll 4
        for (int j = 0; j < 32; ++j) {
            const float p = Ps[r][j];
            const float4 va = *(const float4*)&Vs[j][c0];
            const float4 vb = *(const float4*)&Vs[j][c0 + 4];
            O[0] += p * va.x; O[1] += p * va.y; O[2] += p * va.z; O[3] += p * va.w;
            O[4] += p * vb.x; O[5] += p * vb.y; O[6] += p * vb.z; O[7] += p * vb.w;
        }
        m_old = m_new;
    }

    const float inv = 1.0f / l;
    const size_t t = (size_t)(b * SS + q_row0 + r);
    float* dst = att + (t * NHH + h) * 128 + g * 8;
    float4 o0 = make_float4(O[0] * inv, O[1] * inv, O[2] * inv, O[3] * inv);
    float4 o1 = make_float4(O[4] * inv, O[5] * inv, O[6] * inv, O[7] * inv);
    *(float4*)&dst[0] = o0;
    *(float4*)&dst[4] = o1;
}

// ---------------------------------------------------------------------------
extern "C" void kernel_launch(void* const* d_in, const int* in_sizes, int n_in,
                              void* d_out, int out_size, void* d_ws, size_t ws_size,
                              hipStream_t stream) {
    (void)in_sizes; (void)n_in; (void)out_size; (void)ws_size;
    const float* x        = (const float*)d_in[0];
    const float* wq_down  = (const float*)d_in[1];
    const float* wq_up    = (const float*)d_in[2];
    const float* wq_rope  = (const float*)d_in[3];
    const float* q_norm_w = (const float*)d_in[4];
    const float* wkv_down = (const float*)d_in[5];
    const float* kv_norm_w= (const float*)d_in[6];
    const float* wkv_up   = (const float*)d_in[7];
    const float* wk_rope  = (const float*)d_in[8];
    const float* wo       = (const float*)d_in[9];
    float* out = (float*)d_out;

    char* ws = (char*)d_ws;
    // layout (bytes):
    float* q_c   = (float*)(ws + 0);           // 4096x1536 = 25165824 B
    float* kv_c  = (float*)(ws + 25165824);    // 4096x512  =  8388608 B
    float* att   = (float*)(ws + 0);           // 4096x2048 aliases q_c+kv_c (dead by then)
    float* krope = (float*)(ws + 33554432);    // 4096x64   =  1048576 B
    float* qbuf  = (float*)(ws + 34603008);    // 4096x3072 = 50331648 B
    float* vbuf  = (float*)(ws + 84934656);    // 4096x2048 = 33554432 B
    float* knope = (float*)d_out;              // 4096x2048: d_out is dead until final GEMM

    const dim3 blk(256);

    // x -> q_c (pre-norm), kv_c (pre-norm), k_rope (roped)
    gemm_nt<0><<<dim3(1536 / 64, TT / 64), blk, 0, stream>>>(x, wq_down, q_c, nullptr, TT, 1536, 2048);
    gemm_nt<0><<<dim3(512 / 64,  TT / 64), blk, 0, stream>>>(x, wkv_down, kv_c, nullptr, TT, 512, 2048);
    gemm_nt<4><<<dim3(1,         TT / 64), blk, 0, stream>>>(x, wk_rope, krope, nullptr, TT, 64, 2048);

    rmsnorm_k<<<dim3(TT), blk, 0, stream>>>(q_c, q_norm_w, 1536);
    rmsnorm_k<<<dim3(TT), blk, 0, stream>>>(kv_c, kv_norm_w, 512);

    // q_c -> q (nope part scaled, rope part roped+scaled)
    gemm_nt<1><<<dim3(2048 / 64, TT / 64), blk, 0, stream>>>(q_c, wq_up, qbuf, nullptr, TT, 2048, 1536);
    gemm_nt<2><<<dim3(1024 / 64, TT / 64), blk, 0, stream>>>(q_c, wq_rope, qbuf, nullptr, TT, 1024, 1536);

    // kv_c -> k_nope (into d_out scratch), v
    gemm_nt<3><<<dim3(4096 / 64, TT / 64), blk, 0, stream>>>(kv_c, wkv_up, knope, vbuf, TT, 4096, 512);

    // attention
    attn_k<<<dim3(SS / 16, NHH, BBATCH), blk, 0, stream>>>(qbuf, knope, krope, vbuf, att);

    // att @ wo^T -> out
    gemm_nt<0><<<dim3(2048 / 64, TT / 64), blk, 0, stream>>>(att, wo, out, nullptr, TT, 2048, 2048);
}

// Round 2
// 2519.632 us; speedup vs baseline: 1.9828x; 1.9828x over previous
//
#include <hip/hip_runtime.h>
#include <hip/hip_bf16.h>
#include <math.h>

// Problem constants
#define NHH 16
#define SS  2048
#define TT  4096            // B*S tokens
#define DQK 192
#define QSCALE 0.07216878364870322f   // 1/sqrt(192)
#define ROPE_C 0.28782313662425574f   // 2*ln(10000)/64

typedef __bf16 bf16x8 __attribute__((ext_vector_type(8)));
typedef float f32x4 __attribute__((ext_vector_type(4)));

__device__ __forceinline__ void rope_pair(float ce, float co, int fi, int spos,
                                          float& oe, float& oo) {
    float freq = __expf(-ROPE_C * (float)fi);
    float ang  = (float)spos * freq;
    float s = __sinf(ang), c = __cosf(ang);
    oe = ce * c - co * s;
    oo = ce * s + co * c;
}

// ---------------------------------------------------------------------------
// Generic fp32 NT GEMM: C[m][n] = sum_k A[m*K+k] * W[n*K+k]
// MODE epilogues:
//  0: plain fp32 C[m*N+n]
//  1: q_nope scaled -> bf16 q[m*3072 + (n>>7)*192 + (n&127)]
//  2: q_rope rope+scale -> bf16 q[m*3072 + (n>>6)*192 + 128 + (n&63)]
//  3: kv_up split -> bf16 k_nope[m*2048 + h*128 + off], bf16 vT[((b*16+h)*128+c)*2048 + s]
//  4: k_rope rope -> bf16 C[m*64 + n]
// ---------------------------------------------------------------------------
template<int MODE>
__global__ __launch_bounds__(256) void gemm_nt(
        const float* __restrict__ A, const float* __restrict__ W,
        float* __restrict__ C, float* __restrict__ C2,
        int M, int N, int K) {
    __shared__ float As[16][68];
    __shared__ float Bs[16][68];
    const int tid = threadIdx.x;
    const int tx = tid & 15;
    const int ty = tid >> 4;
    const int m0 = blockIdx.y * 64;
    const int n0 = blockIdx.x * 64;

    float acc[4][4];
#pragma unroll
    for (int i = 0; i < 4; ++i)
#pragma unroll
        for (int j = 0; j < 4; ++j) acc[i][j] = 0.f;

    const int lm = tid >> 2;
    const int lk = (tid & 3) << 2;
    const float* Aptr = A + (size_t)(m0 + lm) * K + lk;
    const float* Bptr = W + (size_t)(n0 + lm) * K + lk;

    for (int k0 = 0; k0 < K; k0 += 16) {
        const float4 av = *(const float4*)(Aptr + k0);
        const float4 bv = *(const float4*)(Bptr + k0);
        __syncthreads();
        As[lk + 0][lm] = av.x; As[lk + 1][lm] = av.y;
        As[lk + 2][lm] = av.z; As[lk + 3][lm] = av.w;
        Bs[lk + 0][lm] = bv.x; Bs[lk + 1][lm] = bv.y;
        Bs[lk + 2][lm] = bv.z; Bs[lk + 3][lm] = bv.w;
        __syncthreads();
#pragma unroll
        for (int kk = 0; kk < 16; ++kk) {
            const float4 a4 = *(const float4*)&As[kk][ty << 2];
            const float4 b4 = *(const float4*)&Bs[kk][tx << 2];
            const float a[4] = {a4.x, a4.y, a4.z, a4.w};
            const float b[4] = {b4.x, b4.y, b4.z, b4.w};
#pragma unroll
            for (int i = 0; i < 4; ++i)
#pragma unroll
                for (int j = 0; j < 4; ++j)
                    acc[i][j] = fmaf(a[i], b[j], acc[i][j]);
        }
    }

#pragma unroll
    for (int i = 0; i < 4; ++i) {
        const int m = m0 + (ty << 2) + i;
        if (MODE == 0) {
            float4 v = make_float4(acc[i][0], acc[i][1], acc[i][2], acc[i][3]);
            *(float4*)&C[(size_t)m * N + n0 + (tx << 2)] = v;
        } else if (MODE == 1) {
            __bf16* Cb = (__bf16*)C;
#pragma unroll
            for (int j = 0; j < 4; ++j) {
                const int n = n0 + (tx << 2) + j;
                Cb[(size_t)m * 3072 + (n >> 7) * 192 + (n & 127)] = (__bf16)(acc[i][j] * QSCALE);
            }
        } else if (MODE == 2) {
            __bf16* Cb = (__bf16*)C;
            const int spos = m & (SS - 1);
#pragma unroll
            for (int j = 0; j < 4; j += 2) {
                const int ne = n0 + (tx << 2) + j;
                const int fi = (ne & 63) >> 1;
                float oe, oo;
                rope_pair(acc[i][j], acc[i][j + 1], fi, spos, oe, oo);
                __bf16* dst = Cb + (size_t)m * 3072 + (ne >> 6) * 192 + 128 + (ne & 63);
                dst[0] = (__bf16)(oe * QSCALE);
                dst[1] = (__bf16)(oo * QSCALE);
            }
        } else if (MODE == 3) {
            __bf16* Kb = (__bf16*)C;
            __bf16* Vt = (__bf16*)C2;
            const int bb = m >> 11;           // batch
            const int ss = m & (SS - 1);      // seq pos
#pragma unroll
            for (int j = 0; j < 4; ++j) {
                const int n = n0 + (tx << 2) + j;
                const int h = n >> 8, off = n & 255;
                if (off < 128)
                    Kb[(size_t)m * 2048 + h * 128 + off] = (__bf16)acc[i][j];
                else
                    Vt[(((size_t)bb * NHH + h) * 128 + (off - 128)) * SS + ss] = (__bf16)acc[i][j];
            }
        } else if (MODE == 4) {
            __bf16* Cb = (__bf16*)C;
            const int spos = m & (SS - 1);
#pragma unroll
            for (int j = 0; j < 4; j += 2) {
                const int ne = n0 + (tx << 2) + j;
                const int fi = ne >> 1;
                float oe, oo;
                rope_pair(acc[i][j], acc[i][j + 1], fi, spos, oe, oo);
                Cb[(size_t)m * 64 + ne]     = (__bf16)oe;
                Cb[(size_t)m * 64 + ne + 1] = (__bf16)oo;
            }
        }
    }
}

// ---------------------------------------------------------------------------
// RMSNorm (in place)
// ---------------------------------------------------------------------------
__global__ __launch_bounds__(256) void rmsnorm_k(float* __restrict__ x,
                                                 const float* __restrict__ w,
                                                 int N) {
    const int row = blockIdx.x;
    float* xr = x + (size_t)row * N;
    float ss = 0.f;
    for (int i = threadIdx.x; i < N; i += 256) {
        float v = xr[i];
        ss += v * v;
    }
    __shared__ float red[256];
    red[threadIdx.x] = ss;
    __syncthreads();
    for (int s = 128; s > 0; s >>= 1) {
        if (threadIdx.x < s) red[threadIdx.x] += red[threadIdx.x + s];
        __syncthreads();
    }
    const float scale = rsqrtf(red[0] / (float)N + 1e-6f);
    for (int i = threadIdx.x; i < N; i += 256) xr[i] = xr[i] * scale * w[i];
}

// ---------------------------------------------------------------------------
// MFMA flash attention (bf16 inputs, fp32 accum), causal.
// Grid: (S/64, NH, B), 256 thr = 4 waves. Wave w owns q rows qt*64+w*16..+15.
// q already scaled. No __syncthreads: all state wave-private.
//  q:     [t][h][192] bf16
//  knope: [t][h][128] bf16
//  krope: [t][64]     bf16
//  vT:    [b][h][128][2048] bf16 (transposed V)
//  att:   [t][h][128] fp32
// mfma_f32_16x16x32_bf16 layouts:
//  A: lane holds row=l&15,  k=(l>>4)*8+j  (16B contiguous row-major read)
//  B: lane holds col=l&15,  k=(l>>4)*8+j
//  D: lane holds col=l&15, rows=(l>>4)*4+reg
// ---------------------------------------------------------------------------
__global__ __launch_bounds__(256) void attn_mfma(
        const __bf16* __restrict__ q, const __bf16* __restrict__ knope,
        const __bf16* __restrict__ krope, const __bf16* __restrict__ vT,
        float* __restrict__ att) {
    const int qt = blockIdx.x;
    const int h  = blockIdx.y;
    const int b  = blockIdx.z;
    const int tid = threadIdx.x;
    const int w  = tid >> 6;
    const int l  = tid & 63;
    const int lr = l & 15;
    const int lg = l >> 4;

    __shared__ __bf16 Plds[4][16][40];   // per-wave P tile, pitch 40 (80B, 16B-aligned rows)

    const int qrow0 = qt * 64 + w * 16;

    // Q fragments: 6 chunks of 32 along d
    bf16x8 qf[6];
    const __bf16* qbase = q + (((size_t)(b * SS + qrow0 + lr)) * NHH + h) * DQK + lg * 8;
#pragma unroll
    for (int c = 0; c < 6; ++c)
        qf[c] = *reinterpret_cast<const bf16x8*>(qbase + c * 32);

    f32x4 O[8];
#pragma unroll
    for (int n = 0; n < 8; ++n) O[n] = (f32x4){0.f, 0.f, 0.f, 0.f};
    float m_r[4], l_r[4];
#pragma unroll
    for (int r = 0; r < 4; ++r) { m_r[r] = -INFINITY; l_r[r] = 0.f; }

    const __bf16* vTb = vT + (((size_t)b * NHH + h) * 128 + lr) * SS + lg * 8;

    const int nkt = (qrow0 + 15) / 32 + 1;
    for (int kt = 0; kt < nkt; ++kt) {
        const int kv0 = kt * 32;

        // V fragments for this tile (issue early; independent of scores)
        bf16x8 vf[8];
#pragma unroll
        for (int n = 0; n < 8; ++n)
            vf[n] = *reinterpret_cast<const bf16x8*>(vTb + (size_t)n * 16 * SS + kv0);

        // QK^T: scores D[16q][16k] x2 subtiles
        f32x4 sc[2];
#pragma unroll
        for (int s = 0; s < 2; ++s) {
            sc[s] = (f32x4){0.f, 0.f, 0.f, 0.f};
            const int t = b * SS + kv0 + s * 16 + lr;
            const __bf16* kn = knope + ((size_t)t * NHH + h) * 128 + lg * 8;
            const __bf16* kr = krope + (size_t)t * 64 + lg * 8;
#pragma unroll
            for (int c = 0; c < 4; ++c) {
                bf16x8 kf = *reinterpret_cast<const bf16x8*>(kn + c * 32);
                sc[s] = __builtin_amdgcn_mfma_f32_16x16x32_bf16(qf[c], kf, sc[s], 0, 0, 0);
            }
#pragma unroll
            for (int c = 0; c < 2; ++c) {
                bf16x8 kf = *reinterpret_cast<const bf16x8*>(kr + c * 32);
                sc[s] = __builtin_amdgcn_mfma_f32_16x16x32_bf16(qf[4 + c], kf, sc[s], 0, 0, 0);
            }
        }

        // causal mask: col = kv0 + s*16 + lr, row = qrow0 + lg*4 + r
#pragma unroll
        for (int s = 0; s < 2; ++s) {
            const int kcol = kv0 + s * 16 + lr;
#pragma unroll
            for (int r = 0; r < 4; ++r) {
                if (kcol > qrow0 + lg * 4 + r) sc[s][r] = -INFINITY;
            }
        }

        // online softmax (row stats across the 16 lanes of each row group)
        float al[4];
#pragma unroll
        for (int r = 0; r < 4; ++r) {
            float m = fmaxf(sc[0][r], sc[1][r]);
            m = fmaxf(m, __shfl_xor(m, 1));
            m = fmaxf(m, __shfl_xor(m, 2));
            m = fmaxf(m, __shfl_xor(m, 4));
            m = fmaxf(m, __shfl_xor(m, 8));
            const float mn = fmaxf(m_r[r], m);
            al[r] = __expf(m_r[r] - mn);
            m_r[r] = mn;
        }
#pragma unroll
        for (int s = 0; s < 2; ++s) {
#pragma unroll
            for (int r = 0; r < 4; ++r) {
                const float p = __expf(sc[s][r] - m_r[r]);
                sc[s][r] = p;
                Plds[w][lg * 4 + r][s * 16 + lr] = (__bf16)p;
            }
        }
#pragma unroll
        for (int r = 0; r < 4; ++r) {
            float ls = sc[0][r] + sc[1][r];
            ls += __shfl_xor(ls, 1);
            ls += __shfl_xor(ls, 2);
            ls += __shfl_xor(ls, 4);
            ls += __shfl_xor(ls, 8);
            l_r[r] = l_r[r] * al[r] + ls;
        }
#pragma unroll
        for (int n = 0; n < 8; ++n)
#pragma unroll
            for (int r = 0; r < 4; ++r) O[n][r] *= al[r];

        // P as A-fragment (wave-private LDS round-trip)
        const bf16x8 pf = *reinterpret_cast<const bf16x8*>(&Plds[w][lr][lg * 8]);
#pragma unroll
        for (int n = 0; n < 8; ++n)
            O[n] = __builtin_amdgcn_mfma_f32_16x16x32_bf16(pf, vf[n], O[n], 0, 0, 0);
    }

    // epilogue: normalize and store fp32 att
    float inv[4];
#pragma unroll
    for (int r = 0; r < 4; ++r) inv[r] = 1.0f / l_r[r];
#pragma unroll
    for (int n = 0; n < 8; ++n) {
#pragma unroll
        for (int r = 0; r < 4; ++r) {
            const size_t t = (size_t)(b * SS + qrow0 + lg * 4 + r);
            att[(t * NHH + h) * 128 + n * 16 + lr] = O[n][r] * inv[r];
        }
    }
}

// ---------------------------------------------------------------------------
extern "C" void kernel_launch(void* const* d_in, const int* in_sizes, int n_in,
                              void* d_out, int out_size, void* d_ws, size_t ws_size,
                              hipStream_t stream) {
    (void)in_sizes; (void)n_in; (void)out_size; (void)ws_size;
    const float* x        = (const float*)d_in[0];
    const float* wq_down  = (const float*)d_in[1];
    const float* wq_up    = (const float*)d_in[2];
    const float* wq_rope  = (const float*)d_in[3];
    const float* q_norm_w = (const float*)d_in[4];
    const float* wkv_down = (const float*)d_in[5];
    const float* kv_norm_w= (const float*)d_in[6];
    const float* wkv_up   = (const float*)d_in[7];
    const float* wk_rope  = (const float*)d_in[8];
    const float* wo       = (const float*)d_in[9];
    float* out = (float*)d_out;

    char* ws = (char*)d_ws;
    float*  q_c   = (float*)(ws + 0);            // 4096x1536 f32 = 25165824 B
    float*  kv_c  = (float*)(ws + 25165824);     // 4096x512  f32 =  8388608 B
    float*  att   = (float*)(ws + 0);            // 4096x2048 f32, aliases q_c+kv_c (dead)
    __bf16* krope = (__bf16*)(ws + 33554432);    // 4096x64   bf16 = 524288 B
    __bf16* qbuf  = (__bf16*)(ws + 34078720);    // 4096x3072 bf16 = 25165824 B
    __bf16* vT    = (__bf16*)(ws + 59244544);    // 2x16x128x2048 bf16 = 16777216 B
    __bf16* knope = (__bf16*)d_out;              // 4096x2048 bf16 (d_out scratch, dead until final GEMM)

    const dim3 blk(256);

    gemm_nt<0><<<dim3(1536 / 64, TT / 64), blk, 0, stream>>>(x, wq_down, q_c, nullptr, TT, 1536, 2048);
    gemm_nt<0><<<dim3(512 / 64,  TT / 64), blk, 0, stream>>>(x, wkv_down, kv_c, nullptr, TT, 512, 2048);
    gemm_nt<4><<<dim3(1,         TT / 64), blk, 0, stream>>>(x, wk_rope, (float*)krope, nullptr, TT, 64, 2048);

    rmsnorm_k<<<dim3(TT), blk, 0, stream>>>(q_c, q_norm_w, 1536);
    rmsnorm_k<<<dim3(TT), blk, 0, stream>>>(kv_c, kv_norm_w, 512);

    gemm_nt<1><<<dim3(2048 / 64, TT / 64), blk, 0, stream>>>(q_c, wq_up, (float*)qbuf, nullptr, TT, 2048, 1536);
    gemm_nt<2><<<dim3(1024 / 64, TT / 64), blk, 0, stream>>>(q_c, wq_rope, (float*)qbuf, nullptr, TT, 1024, 1536);

    gemm_nt<3><<<dim3(4096 / 64, TT / 64), blk, 0, stream>>>(kv_c, wkv_up, (float*)knope, (float*)vT, TT, 4096, 512);

    attn_mfma<<<dim3(SS / 64, NHH, 2), blk, 0, stream>>>(qbuf, knope, krope, vT, att);

    gemm_nt<0><<<dim3(2048 / 64, TT / 64), blk, 0, stream>>>(att, wo, out, nullptr, TT, 2048, 2048);
}

// Round 3
// 907.294 us; speedup vs baseline: 5.5064x; 2.7771x over previous
//
#include <hip/hip_runtime.h>
#include <hip/hip_bf16.h>
#include <math.h>

#define NHH 16
#define SS  2048
#define TT  4096            // B*S tokens
#define DQK 192
#define QSCALE 0.07216878364870322f   // 1/sqrt(192)
#define ROPE_C 0.28782313662425574f   // 2*ln(10000)/64

typedef __bf16 bf16x8 __attribute__((ext_vector_type(8)));
typedef float f32x4 __attribute__((ext_vector_type(4)));

#define GLOAD16(gp, lp) __builtin_amdgcn_global_load_lds( \
    (const __attribute__((address_space(1))) void*)(gp),  \
    (__attribute__((address_space(3))) void*)(lp), 16, 0, 0)

// ---------------------------------------------------------------------------
// fp32 -> bf16 cast, 8 elems/thread. n must be a multiple of 2048.
// ---------------------------------------------------------------------------
__global__ __launch_bounds__(256) void cast_f32_bf16(const float* __restrict__ in,
                                                     __bf16* __restrict__ out, int n) {
    const int i = (blockIdx.x * 256 + threadIdx.x) * 8;
    const float4 a = *(const float4*)(in + i);
    const float4 b = *(const float4*)(in + i + 4);
    __bf16 o[8] = {(__bf16)a.x, (__bf16)a.y, (__bf16)a.z, (__bf16)a.w,
                   (__bf16)b.x, (__bf16)b.y, (__bf16)b.z, (__bf16)b.w};
    *(bf16x8*)(out + i) = *(const bf16x8*)o;
}

// ---------------------------------------------------------------------------
// RMSNorm: fp32 in -> bf16 out
// ---------------------------------------------------------------------------
__global__ __launch_bounds__(256) void rmsnorm_k(const float* __restrict__ in,
                                                 __bf16* __restrict__ out,
                                                 const float* __restrict__ w, int N) {
    const int row = blockIdx.x;
    const float* xr = in + (size_t)row * N;
    float ss = 0.f;
    for (int i = threadIdx.x; i < N; i += 256) {
        float v = xr[i];
        ss += v * v;
    }
    __shared__ float red[256];
    red[threadIdx.x] = ss;
    __syncthreads();
    for (int s = 128; s > 0; s >>= 1) {
        if (threadIdx.x < s) red[threadIdx.x] += red[threadIdx.x + s];
        __syncthreads();
    }
    const float scale = rsqrtf(red[0] / (float)N + 1e-6f);
    __bf16* orow = out + (size_t)row * N;
    for (int i = threadIdx.x; i < N; i += 256) orow[i] = (__bf16)(xr[i] * scale * w[i]);
}

// ---------------------------------------------------------------------------
// bf16 MFMA NT-GEMM, m97 structure: 128x128 tile, BK=32, 4 waves (2x2),
// global_load_lds width-16 staging, 2 barriers per K-step.
// A: [M][K] bf16 row-major. Weights W*: [n][K] bf16 row-major.
// MODE 0 (X-GEMM, N=2112 pad->2176): n<1536: W0->q_c fp32 F0[m*1536+n]
//        1536<=n<2048: W1->kv_c fp32 F1[m*512+n-1536]
//        2048<=n<2112: W2->krope bf16 roped B0[m*64+(n-2048)]
// MODE 1 (Q-GEMM, N=3072): n<2048: W0-> qbuf scatter scaled
//        n>=2048: W1-> qbuf rope+scale
// MODE 2 (KV-GEMM, N=4096): W0 -> knope B0 / vT B1 split
// MODE 3 (O-GEMM): plain fp32 F0[m*N+n]
// ---------------------------------------------------------------------------
template<int MODE>
__global__ __launch_bounds__(256) void gemm_mfma(
        const __bf16* __restrict__ A,
        const __bf16* __restrict__ W0, const __bf16* __restrict__ W1,
        const __bf16* __restrict__ W2,
        float* __restrict__ F0, float* __restrict__ F1,
        __bf16* __restrict__ B0, __bf16* __restrict__ B1,
        int M, int N, int K) {
    __shared__ __bf16 As[128 * 32];
    __shared__ __bf16 Bs[128 * 32];
    const int tid = threadIdx.x;
    const int w = tid >> 6, l = tid & 63;
    const int lr = l & 15, lg = l >> 4;
    const int wr = w >> 1, wc = w & 1;
    const int m0 = blockIdx.y * 128;
    const int n0 = blockIdx.x * 128;

    // staging: wave w covers tile rows [w*32, w*32+32), two 16-row calls
    const int sr = l >> 2;            // 0..15
    const int sc = (l & 3) * 8;       // 0,8,16,24
    const __bf16* ag[2];
    const __bf16* bg[2];
    __bf16* asd[2];
    __bf16* bsd[2];
#pragma unroll
    for (int c = 0; c < 2; ++c) {
        const int arow = m0 + w * 32 + c * 16 + sr;
        ag[c] = A + (size_t)arow * K + sc;
        const int n = n0 + w * 32 + c * 16 + sr;
        const __bf16* wp;
        if (MODE == 0) {
            if (n < 1536)      wp = W0 + (size_t)n * K;
            else if (n < 2048) wp = W1 + (size_t)(n - 1536) * K;
            else if (n < 2112) wp = W2 + (size_t)(n - 2048) * K;
            else               wp = W0;                     // clamp (masked at store)
        } else if (MODE == 1) {
            wp = (n < 2048) ? W0 + (size_t)n * K : W1 + (size_t)(n - 2048) * K;
        } else {
            wp = W0 + (size_t)n * K;
        }
        bg[c] = wp + sc;
        asd[c] = &As[(w * 32 + c * 16) * 32];
        bsd[c] = &Bs[(w * 32 + c * 16) * 32];
    }

    f32x4 acc[4][4];
#pragma unroll
    for (int i = 0; i < 4; ++i)
#pragma unroll
        for (int j = 0; j < 4; ++j) acc[i][j] = (f32x4){0.f, 0.f, 0.f, 0.f};

    for (int k0 = 0; k0 < K; k0 += 32) {
        GLOAD16(ag[0] + k0, asd[0]);
        GLOAD16(ag[1] + k0, asd[1]);
        GLOAD16(bg[0] + k0, bsd[0]);
        GLOAD16(bg[1] + k0, bsd[1]);
        __syncthreads();
        bf16x8 af[4], bfr[4];
#pragma unroll
        for (int i = 0; i < 4; ++i)
            af[i] = *(const bf16x8*)&As[(wr * 64 + i * 16 + lr) * 32 + lg * 8];
#pragma unroll
        for (int j = 0; j < 4; ++j)
            bfr[j] = *(const bf16x8*)&Bs[(wc * 64 + j * 16 + lr) * 32 + lg * 8];
#pragma unroll
        for (int i = 0; i < 4; ++i)
#pragma unroll
            for (int j = 0; j < 4; ++j)
                acc[i][j] = __builtin_amdgcn_mfma_f32_16x16x32_bf16(af[i], bfr[j], acc[i][j], 0, 0, 0);
        __syncthreads();
    }

    // epilogue: D elem (i,j,r): row m = m0+wr*64+i*16+lg*4+r, col n = n0+wc*64+j*16+lr
#pragma unroll
    for (int i = 0; i < 4; ++i) {
#pragma unroll
        for (int j = 0; j < 4; ++j) {
#pragma unroll
            for (int r = 0; r < 4; ++r) {
                const int m = m0 + wr * 64 + i * 16 + lg * 4 + r;
                const int n = n0 + wc * 64 + j * 16 + lr;
                const float v = acc[i][j][r];
                float vp = 0.f;
                if (MODE == 0 || MODE == 1) vp = __shfl_xor(v, 1);  // rope partner
                if (MODE == 0) {
                    if (n < 1536) {
                        F0[(size_t)m * 1536 + n] = v;
                    } else if (n < 2048) {
                        F1[(size_t)m * 512 + (n - 1536)] = v;
                    } else if (n < 2112) {
                        const int jj = n - 2048;            // 0..63
                        const int fi = jj >> 1;
                        const int spos = m & (SS - 1);
                        const float freq = __expf(-ROPE_C * (float)fi);
                        const float ang = (float)spos * freq;
                        const float sn = __sinf(ang), cs = __cosf(ang);
                        const float o = (jj & 1) ? (vp * sn + v * cs) : (v * cs - vp * sn);
                        B0[(size_t)m * 64 + jj] = (__bf16)o;
                    }
                } else if (MODE == 1) {
                    if (n < 2048) {
                        B0[(size_t)m * 3072 + (n >> 7) * 192 + (n & 127)] = (__bf16)(v * QSCALE);
                    } else {
                        const int jj = n - 2048;            // 0..1023
                        const int h = jj >> 6, dd = jj & 63;
                        const int fi = dd >> 1;
                        const int spos = m & (SS - 1);
                        const float freq = __expf(-ROPE_C * (float)fi);
                        const float ang = (float)spos * freq;
                        const float sn = __sinf(ang), cs = __cosf(ang);
                        const float o = (dd & 1) ? (vp * sn + v * cs) : (v * cs - vp * sn);
                        B0[(size_t)m * 3072 + h * 192 + 128 + dd] = (__bf16)(o * QSCALE);
                    }
                } else if (MODE == 2) {
                    const int h = n >> 8, off = n & 255;
                    if (off < 128)
                        B0[(size_t)m * 2048 + h * 128 + off] = (__bf16)v;
                    else
                        B1[(((size_t)(m >> 11) * NHH + h) * 128 + (off - 128)) * SS + (m & (SS - 1))] = (__bf16)v;
                } else {
                    F0[(size_t)m * N + n] = v;
                }
            }
        }
    }
}

// ---------------------------------------------------------------------------
// MFMA flash attention (bf16 in, fp32 accum, bf16 out), causal. Unchanged
// from round 2 except att output is bf16.
// ---------------------------------------------------------------------------
__global__ __launch_bounds__(256) void attn_mfma(
        const __bf16* __restrict__ q, const __bf16* __restrict__ knope,
        const __bf16* __restrict__ krope, const __bf16* __restrict__ vT,
        __bf16* __restrict__ att) {
    const int qt = blockIdx.x;
    const int h  = blockIdx.y;
    const int b  = blockIdx.z;
    const int tid = threadIdx.x;
    const int w  = tid >> 6;
    const int l  = tid & 63;
    const int lr = l & 15;
    const int lg = l >> 4;

    __shared__ __bf16 Plds[4][16][40];

    const int qrow0 = qt * 64 + w * 16;

    bf16x8 qf[6];
    const __bf16* qbase = q + (((size_t)(b * SS + qrow0 + lr)) * NHH + h) * DQK + lg * 8;
#pragma unroll
    for (int c = 0; c < 6; ++c)
        qf[c] = *reinterpret_cast<const bf16x8*>(qbase + c * 32);

    f32x4 O[8];
#pragma unroll
    for (int n = 0; n < 8; ++n) O[n] = (f32x4){0.f, 0.f, 0.f, 0.f};
    float m_r[4], l_r[4];
#pragma unroll
    for (int r = 0; r < 4; ++r) { m_r[r] = -INFINITY; l_r[r] = 0.f; }

    const __bf16* vTb = vT + (((size_t)b * NHH + h) * 128 + lr) * SS + lg * 8;

    const int nkt = (qrow0 + 15) / 32 + 1;
    for (int kt = 0; kt < nkt; ++kt) {
        const int kv0 = kt * 32;

        bf16x8 vf[8];
#pragma unroll
        for (int n = 0; n < 8; ++n)
            vf[n] = *reinterpret_cast<const bf16x8*>(vTb + (size_t)n * 16 * SS + kv0);

        f32x4 sc[2];
#pragma unroll
        for (int s = 0; s < 2; ++s) {
            sc[s] = (f32x4){0.f, 0.f, 0.f, 0.f};
            const int t = b * SS + kv0 + s * 16 + lr;
            const __bf16* kn = knope + ((size_t)t * NHH + h) * 128 + lg * 8;
            const __bf16* kr = krope + (size_t)t * 64 + lg * 8;
#pragma unroll
            for (int c = 0; c < 4; ++c) {
                bf16x8 kf = *reinterpret_cast<const bf16x8*>(kn + c * 32);
                sc[s] = __builtin_amdgcn_mfma_f32_16x16x32_bf16(qf[c], kf, sc[s], 0, 0, 0);
            }
#pragma unroll
            for (int c = 0; c < 2; ++c) {
                bf16x8 kf = *reinterpret_cast<const bf16x8*>(kr + c * 32);
                sc[s] = __builtin_amdgcn_mfma_f32_16x16x32_bf16(qf[4 + c], kf, sc[s], 0, 0, 0);
            }
        }

#pragma unroll
        for (int s = 0; s < 2; ++s) {
            const int kcol = kv0 + s * 16 + lr;
#pragma unroll
            for (int r = 0; r < 4; ++r) {
                if (kcol > qrow0 + lg * 4 + r) sc[s][r] = -INFINITY;
            }
        }

        float al[4];
#pragma unroll
        for (int r = 0; r < 4; ++r) {
            float m = fmaxf(sc[0][r], sc[1][r]);
            m = fmaxf(m, __shfl_xor(m, 1));
            m = fmaxf(m, __shfl_xor(m, 2));
            m = fmaxf(m, __shfl_xor(m, 4));
            m = fmaxf(m, __shfl_xor(m, 8));
            const float mn = fmaxf(m_r[r], m);
            al[r] = __expf(m_r[r] - mn);
            m_r[r] = mn;
        }
#pragma unroll
        for (int s = 0; s < 2; ++s) {
#pragma unroll
            for (int r = 0; r < 4; ++r) {
                const float p = __expf(sc[s][r] - m_r[r]);
                sc[s][r] = p;
                Plds[w][lg * 4 + r][s * 16 + lr] = (__bf16)p;
            }
        }
#pragma unroll
        for (int r = 0; r < 4; ++r) {
            float ls = sc[0][r] + sc[1][r];
            ls += __shfl_xor(ls, 1);
            ls += __shfl_xor(ls, 2);
            ls += __shfl_xor(ls, 4);
            ls += __shfl_xor(ls, 8);
            l_r[r] = l_r[r] * al[r] + ls;
        }
#pragma unroll
        for (int n = 0; n < 8; ++n)
#pragma unroll
            for (int r = 0; r < 4; ++r) O[n][r] *= al[r];

        const bf16x8 pf = *reinterpret_cast<const bf16x8*>(&Plds[w][lr][lg * 8]);
#pragma unroll
        for (int n = 0; n < 8; ++n)
            O[n] = __builtin_amdgcn_mfma_f32_16x16x32_bf16(pf, vf[n], O[n], 0, 0, 0);
    }

    float inv[4];
#pragma unroll
    for (int r = 0; r < 4; ++r) inv[r] = 1.0f / l_r[r];
#pragma unroll
    for (int n = 0; n < 8; ++n) {
#pragma unroll
        for (int r = 0; r < 4; ++r) {
            const size_t t = (size_t)(b * SS + qrow0 + lg * 4 + r);
            att[(t * NHH + h) * 128 + n * 16 + lr] = (__bf16)(O[n][r] * inv[r]);
        }
    }
}

// ---------------------------------------------------------------------------
extern "C" void kernel_launch(void* const* d_in, const int* in_sizes, int n_in,
                              void* d_out, int out_size, void* d_ws, size_t ws_size,
                              hipStream_t stream) {
    (void)in_sizes; (void)n_in; (void)out_size; (void)ws_size;
    const float* x        = (const float*)d_in[0];
    const float* wq_down  = (const float*)d_in[1];
    const float* wq_up    = (const float*)d_in[2];
    const float* wq_rope  = (const float*)d_in[3];
    const float* q_norm_w = (const float*)d_in[4];
    const float* wkv_down = (const float*)d_in[5];
    const float* kv_norm_w= (const float*)d_in[6];
    const float* wkv_up   = (const float*)d_in[7];
    const float* wk_rope  = (const float*)d_in[8];
    const float* wo       = (const float*)d_in[9];
    float* out = (float*)d_out;

    char* ws = (char*)d_ws;
    float*  q_c   = (float*)(ws + 0);            // 24MB fp32 [4096][1536]
    __bf16* att   = (__bf16*)(ws + 0);           // 16MB bf16, aliases dead q_c
    float*  kv_c  = (float*)(ws + 25165824);     // 8MB fp32 [4096][512]
    __bf16* xb    = (__bf16*)(ws + 33554432);    // 16MB bf16 [4096][2048]
    __bf16* vT    = (__bf16*)(ws + 33554432);    // 16MB bf16, aliases dead xb
    __bf16* qc_b  = (__bf16*)(ws + 50331648);    // 12MB bf16 [4096][1536]
    __bf16* kvc_b = (__bf16*)(ws + 62914560);    // 4MB bf16 [4096][512]
    __bf16* krope = (__bf16*)(ws + 67108864);    // 0.5MB bf16 [4096][64]
    __bf16* qbuf  = (__bf16*)(ws + 67633152);    // 24MB bf16 [4096][3072]
    __bf16* wqd_b = (__bf16*)(ws + 92798976);    // 6MB
    __bf16* wqu_b = (__bf16*)(ws + 99090432);    // 6MB
    __bf16* wqr_b = (__bf16*)(ws + 105381888);   // 3MB
    __bf16* wkvd_b= (__bf16*)(ws + 108527616);   // 2MB
    __bf16* wkvu_b= (__bf16*)(ws + 110624768);   // 4MB
    __bf16* wkr_b = (__bf16*)(ws + 114819072);   // 0.25MB  (end 115081216)
    __bf16* wo_b  = (__bf16*)(ws + 99090432);    // 8MB, aliases wqu_b+wqr_b (dead after gemmQ)
    __bf16* knope = (__bf16*)d_out;              // 16MB bf16 in d_out (dead until final GEMM)

    const dim3 blk(256);

    cast_f32_bf16<<<dim3(TT * 2048 / 2048), blk, 0, stream>>>(x, xb, TT * 2048);
    cast_f32_bf16<<<dim3(1536 * 2048 / 2048), blk, 0, stream>>>(wq_down, wqd_b, 1536 * 2048);
    cast_f32_bf16<<<dim3(512 * 2048 / 2048), blk, 0, stream>>>(wkv_down, wkvd_b, 512 * 2048);
    cast_f32_bf16<<<dim3(64 * 2048 / 2048), blk, 0, stream>>>(wk_rope, wkr_b, 64 * 2048);
    cast_f32_bf16<<<dim3(2048 * 1536 / 2048), blk, 0, stream>>>(wq_up, wqu_b, 2048 * 1536);
    cast_f32_bf16<<<dim3(1024 * 1536 / 2048), blk, 0, stream>>>(wq_rope, wqr_b, 1024 * 1536);
    cast_f32_bf16<<<dim3(4096 * 512 / 2048), blk, 0, stream>>>(wkv_up, wkvu_b, 4096 * 512);

    // X-GEMM: xb @ [wq_down | wkv_down | wk_rope]^T -> q_c, kv_c, krope(roped)
    gemm_mfma<0><<<dim3(17, 32), blk, 0, stream>>>(xb, wqd_b, wkvd_b, wkr_b,
                                                   q_c, kv_c, krope, nullptr, TT, 2112, 2048);

    rmsnorm_k<<<dim3(TT), blk, 0, stream>>>(q_c, qc_b, q_norm_w, 1536);
    rmsnorm_k<<<dim3(TT), blk, 0, stream>>>(kv_c, kvc_b, kv_norm_w, 512);

    // Q-GEMM: qc_b @ [wq_up | wq_rope]^T -> qbuf (scatter+rope+scale)
    gemm_mfma<1><<<dim3(24, 32), blk, 0, stream>>>(qc_b, wqu_b, wqr_b, nullptr,
                                                   nullptr, nullptr, qbuf, nullptr, TT, 3072, 1536);

    cast_f32_bf16<<<dim3(2048 * 2048 / 2048), blk, 0, stream>>>(wo, wo_b, 2048 * 2048);

    // KV-GEMM: kvc_b @ wkv_up^T -> knope, vT
    gemm_mfma<2><<<dim3(32, 32), blk, 0, stream>>>(kvc_b, wkvu_b, nullptr, nullptr,
                                                   nullptr, nullptr, knope, vT, TT, 4096, 512);

    attn_mfma<<<dim3(SS / 64, NHH, 2), blk, 0, stream>>>(qbuf, knope, krope, vT, att);

    // O-GEMM: att @ wo^T -> out (fp32)
    gemm_mfma<3><<<dim3(16, 32), blk, 0, stream>>>(att, wo_b, nullptr, nullptr,
                                                   out, nullptr, nullptr, nullptr, TT, 2048, 2048);
}

// Round 4
// 514.399 us; speedup vs baseline: 9.7122x; 1.7638x over previous
//
#include <hip/hip_runtime.h>
#include <hip/hip_bf16.h>
#include <math.h>

#define NHH 16
#define SS  2048
#define TT  4096            // B*S tokens
#define DQK 192
#define QSCALE 0.07216878364870322f   // 1/sqrt(192)
#define ROPE_C 0.28782313662425574f   // 2*ln(10000)/64

typedef __bf16 bf16x8 __attribute__((ext_vector_type(8)));
typedef float f32x4 __attribute__((ext_vector_type(4)));

#define GLOAD16(gp, lp) __builtin_amdgcn_global_load_lds( \
    (const __attribute__((address_space(1))) void*)(gp),  \
    (__attribute__((address_space(3))) void*)(lp), 16, 0, 0)

// ---------------------------------------------------------------------------
// fp32 -> bf16 cast, 8 elems/thread
// ---------------------------------------------------------------------------
__global__ __launch_bounds__(256) void cast_f32_bf16(const float* __restrict__ in,
                                                     __bf16* __restrict__ out, int n) {
    const int i = (blockIdx.x * 256 + threadIdx.x) * 8;
    const float4 a = *(const float4*)(in + i);
    const float4 b = *(const float4*)(in + i + 4);
    __bf16 o[8] = {(__bf16)a.x, (__bf16)a.y, (__bf16)a.z, (__bf16)a.w,
                   (__bf16)b.x, (__bf16)b.y, (__bf16)b.z, (__bf16)b.w};
    *(bf16x8*)(out + i) = *(const bf16x8*)o;
}

// ---------------------------------------------------------------------------
// RMSNorm: fp32 in -> bf16 out
// ---------------------------------------------------------------------------
__global__ __launch_bounds__(256) void rmsnorm_k(const float* __restrict__ in,
                                                 __bf16* __restrict__ out,
                                                 const float* __restrict__ w, int N) {
    const int row = blockIdx.x;
    const float* xr = in + (size_t)row * N;
    float ss = 0.f;
    for (int i = threadIdx.x; i < N; i += 256) {
        float v = xr[i];
        ss += v * v;
    }
    __shared__ float red[256];
    red[threadIdx.x] = ss;
    __syncthreads();
    for (int s = 128; s > 0; s >>= 1) {
        if (threadIdx.x < s) red[threadIdx.x] += red[threadIdx.x + s];
        __syncthreads();
    }
    const float scale = rsqrtf(red[0] / (float)N + 1e-6f);
    __bf16* orow = out + (size_t)row * N;
    for (int i = threadIdx.x; i < N; i += 256) orow[i] = (__bf16)(xr[i] * scale * w[i]);
}

// ---------------------------------------------------------------------------
// bf16 MFMA NT-GEMM (m97 structure), same as round 3.
// ---------------------------------------------------------------------------
template<int MODE>
__global__ __launch_bounds__(256) void gemm_mfma(
        const __bf16* __restrict__ A,
        const __bf16* __restrict__ W0, const __bf16* __restrict__ W1,
        const __bf16* __restrict__ W2,
        float* __restrict__ F0, float* __restrict__ F1,
        __bf16* __restrict__ B0, __bf16* __restrict__ B1,
        int M, int N, int K) {
    __shared__ __bf16 As[128 * 32];
    __shared__ __bf16 Bs[128 * 32];
    const int tid = threadIdx.x;
    const int w = tid >> 6, l = tid & 63;
    const int lr = l & 15, lg = l >> 4;
    const int wr = w >> 1, wc = w & 1;
    const int m0 = blockIdx.y * 128;
    const int n0 = blockIdx.x * 128;

    const int sr = l >> 2;
    const int sc = (l & 3) * 8;
    const __bf16* ag[2];
    const __bf16* bg[2];
    __bf16* asd[2];
    __bf16* bsd[2];
#pragma unroll
    for (int c = 0; c < 2; ++c) {
        const int arow = m0 + w * 32 + c * 16 + sr;
        ag[c] = A + (size_t)arow * K + sc;
        const int n = n0 + w * 32 + c * 16 + sr;
        const __bf16* wp;
        if (MODE == 0) {
            if (n < 1536)      wp = W0 + (size_t)n * K;
            else if (n < 2048) wp = W1 + (size_t)(n - 1536) * K;
            else if (n < 2112) wp = W2 + (size_t)(n - 2048) * K;
            else               wp = W0;
        } else if (MODE == 1) {
            wp = (n < 2048) ? W0 + (size_t)n * K : W1 + (size_t)(n - 2048) * K;
        } else {
            wp = W0 + (size_t)n * K;
        }
        bg[c] = wp + sc;
        asd[c] = &As[(w * 32 + c * 16) * 32];
        bsd[c] = &Bs[(w * 32 + c * 16) * 32];
    }

    f32x4 acc[4][4];
#pragma unroll
    for (int i = 0; i < 4; ++i)
#pragma unroll
        for (int j = 0; j < 4; ++j) acc[i][j] = (f32x4){0.f, 0.f, 0.f, 0.f};

    for (int k0 = 0; k0 < K; k0 += 32) {
        GLOAD16(ag[0] + k0, asd[0]);
        GLOAD16(ag[1] + k0, asd[1]);
        GLOAD16(bg[0] + k0, bsd[0]);
        GLOAD16(bg[1] + k0, bsd[1]);
        __syncthreads();
        bf16x8 af[4], bfr[4];
#pragma unroll
        for (int i = 0; i < 4; ++i)
            af[i] = *(const bf16x8*)&As[(wr * 64 + i * 16 + lr) * 32 + lg * 8];
#pragma unroll
        for (int j = 0; j < 4; ++j)
            bfr[j] = *(const bf16x8*)&Bs[(wc * 64 + j * 16 + lr) * 32 + lg * 8];
#pragma unroll
        for (int i = 0; i < 4; ++i)
#pragma unroll
            for (int j = 0; j < 4; ++j)
                acc[i][j] = __builtin_amdgcn_mfma_f32_16x16x32_bf16(af[i], bfr[j], acc[i][j], 0, 0, 0);
        __syncthreads();
    }

#pragma unroll
    for (int i = 0; i < 4; ++i) {
#pragma unroll
        for (int j = 0; j < 4; ++j) {
#pragma unroll
            for (int r = 0; r < 4; ++r) {
                const int m = m0 + wr * 64 + i * 16 + lg * 4 + r;
                const int n = n0 + wc * 64 + j * 16 + lr;
                const float v = acc[i][j][r];
                float vp = 0.f;
                if (MODE == 0 || MODE == 1) vp = __shfl_xor(v, 1);
                if (MODE == 0) {
                    if (n < 1536) {
                        F0[(size_t)m * 1536 + n] = v;
                    } else if (n < 2048) {
                        F1[(size_t)m * 512 + (n - 1536)] = v;
                    } else if (n < 2112) {
                        const int jj = n - 2048;
                        const int fi = jj >> 1;
                        const int spos = m & (SS - 1);
                        const float freq = __expf(-ROPE_C * (float)fi);
                        const float ang = (float)spos * freq;
                        const float sn = __sinf(ang), cs = __cosf(ang);
                        const float o = (jj & 1) ? (vp * sn + v * cs) : (v * cs - vp * sn);
                        B0[(size_t)m * 64 + jj] = (__bf16)o;
                    }
                } else if (MODE == 1) {
                    if (n < 2048) {
                        B0[(size_t)m * 3072 + (n >> 7) * 192 + (n & 127)] = (__bf16)(v * QSCALE);
                    } else {
                        const int jj = n - 2048;
                        const int h = jj >> 6, dd = jj & 63;
                        const int fi = dd >> 1;
                        const int spos = m & (SS - 1);
                        const float freq = __expf(-ROPE_C * (float)fi);
                        const float ang = (float)spos * freq;
                        const float sn = __sinf(ang), cs = __cosf(ang);
                        const float o = (dd & 1) ? (vp * sn + v * cs) : (v * cs - vp * sn);
                        B0[(size_t)m * 3072 + h * 192 + 128 + dd] = (__bf16)(o * QSCALE);
                    }
                } else if (MODE == 2) {
                    const int h = n >> 8, off = n & 255;
                    if (off < 128)
                        B0[(size_t)m * 2048 + h * 128 + off] = (__bf16)v;
                    else
                        B1[(((size_t)(m >> 11) * NHH + h) * 128 + (off - 128)) * SS + (m & (SS - 1))] = (__bf16)v;
                } else {
                    F0[(size_t)m * N + n] = v;
                }
            }
        }
    }
}

// ---------------------------------------------------------------------------
// MFMA flash attention v2: LDS-staged K/V shared by 4 waves, double-buffered,
// async reg-staging (T14), causal tile-pairing for balance.
// Grid (8, NH, B), 256 thr = 4 waves. Block handles q-tiles {tA, 15-tA} of 128
// rows each, sequentially; wave w owns rows [w*32, w*32+32) of the tile
// (2 frag groups of 16). KV tile = 32.
//  q:     [t][h][192] bf16 (pre-scaled)
//  knope: [t][h*128+d] bf16
//  krope: [t][64] bf16
//  vT:    [(b*16+h)*128 + d][2048] bf16
//  att:   [t][h*128+d] bf16
// ---------------------------------------------------------------------------
__global__ __launch_bounds__(256, 1) void attn_mfma2(
        const __bf16* __restrict__ q, const __bf16* __restrict__ knope,
        const __bf16* __restrict__ krope, const __bf16* __restrict__ vT,
        __bf16* __restrict__ att) {
    const int h  = blockIdx.y;
    const int b  = blockIdx.z;
    const int tid = threadIdx.x;
    const int w  = tid >> 6;
    const int l  = tid & 63;
    const int lr = l & 15;
    const int lg = l >> 4;

    __shared__ __bf16 Ks[2][32][200];   // K tile, pitch 200 elem (400B): 2-way-free banks
    __shared__ __bf16 Vs[2][128][40];   // V^T tile [d][kv], pitch 40 elem (80B)
    __shared__ __bf16 Ps[4][2][16][40]; // per-wave, per-group P

    const int tiles[2] = {(int)blockIdx.x, 15 - (int)blockIdx.x};

    // ---- staging helpers (reg round-trip so LDS layout can be padded) ----
    bf16x8 kreg[3], vreg[2];
    auto stage_load = [&](int kv0) {
#pragma unroll
        for (int i = 0; i < 3; ++i) {
            const int cidx = tid + 256 * i;          // 768 chunks: 32 rows x 24
            const int row = cidx / 24, c16 = cidx - row * 24;
            const size_t t = (size_t)(b * SS + kv0 + row);
            const __bf16* src = (c16 < 16)
                ? knope + t * 2048 + h * 128 + c16 * 8
                : krope + t * 64 + (c16 - 16) * 8;
            kreg[i] = *(const bf16x8*)src;
        }
#pragma unroll
        for (int i = 0; i < 2; ++i) {
            const int cidx = tid + 256 * i;          // 512 chunks: 128 rows x 4
            const int row = cidx >> 2, c16 = cidx & 3;
            vreg[i] = *(const bf16x8*)(vT + (((size_t)b * NHH + h) * 128 + row) * SS
                                          + kv0 + c16 * 8);
        }
    };
    auto stage_write = [&](int bi) {
#pragma unroll
        for (int i = 0; i < 3; ++i) {
            const int cidx = tid + 256 * i;
            const int row = cidx / 24, c16 = cidx - row * 24;
            *(bf16x8*)&Ks[bi][row][c16 * 8] = kreg[i];
        }
#pragma unroll
        for (int i = 0; i < 2; ++i) {
            const int cidx = tid + 256 * i;
            const int row = cidx >> 2, c16 = cidx & 3;
            *(bf16x8*)&Vs[bi][row][c16 * 8] = vreg[i];
        }
    };

    // prologue: stage part 0, tile 0 into buf 0
    stage_load(0);
    stage_write(0);
    __syncthreads();
    int cur = 0;

#pragma unroll
    for (int p = 0; p < 2; ++p) {
        const int rbase = tiles[p] * 128;
        const int rg0 = rbase + w * 32;
        const int nkt = 4 * tiles[p] + 4;

        // Q fragments for both groups
        bf16x8 qf[2][6];
#pragma unroll
        for (int g = 0; g < 2; ++g) {
            const __bf16* qb = q + (((size_t)(b * SS + rg0 + g * 16 + lr)) * NHH + h) * DQK + lg * 8;
#pragma unroll
            for (int c = 0; c < 6; ++c) qf[g][c] = *(const bf16x8*)(qb + c * 32);
        }

        f32x4 O[2][8];
        float m_r[2][4], l_r[2][4];
#pragma unroll
        for (int g = 0; g < 2; ++g) {
#pragma unroll
            for (int n = 0; n < 8; ++n) O[g][n] = (f32x4){0.f, 0.f, 0.f, 0.f};
#pragma unroll
            for (int r = 0; r < 4; ++r) { m_r[g][r] = -INFINITY; l_r[g][r] = 0.f; }
        }

        for (int kt = 0; kt < nkt; ++kt) {
            const int kv0 = kt * 32;
            const bool hasNext = (kt + 1 < nkt) || (p == 0);
            const int nxt = (kt + 1 < nkt) ? (kt + 1) * 32 : 0;
            if (hasNext) stage_load(nxt);            // async: overlaps compute

            const bool act0 = kv0 <= rg0 + 15;
            const bool act1 = kv0 <= rg0 + 31;
            if (act1) {
                // ---- QK^T ----
                f32x4 sc[2][2];
#pragma unroll
                for (int s = 0; s < 2; ++s) {
                    bf16x8 kf[6];
#pragma unroll
                    for (int c = 0; c < 6; ++c)
                        kf[c] = *(const bf16x8*)&Ks[cur][s * 16 + lr][c * 32 + lg * 8];
#pragma unroll
                    for (int g = 0; g < 2; ++g) {
                        if (kv0 + s * 16 <= rg0 + g * 16 + 15) {
                            f32x4 a = (f32x4){0.f, 0.f, 0.f, 0.f};
#pragma unroll
                            for (int c = 0; c < 6; ++c)
                                a = __builtin_amdgcn_mfma_f32_16x16x32_bf16(qf[g][c], kf[c], a, 0, 0, 0);
                            sc[g][s] = a;
                        } else {
                            sc[g][s] = (f32x4){-INFINITY, -INFINITY, -INFINITY, -INFINITY};
                        }
                    }
                }
                // ---- softmax per group ----
#pragma unroll
                for (int g = 0; g < 2; ++g) {
                    const bool actg = (g == 0) ? act0 : act1;
                    if (!actg) continue;
                    const int rg = rg0 + g * 16;
#pragma unroll
                    for (int s = 0; s < 2; ++s) {
                        const int col = kv0 + s * 16 + lr;
#pragma unroll
                        for (int r = 0; r < 4; ++r)
                            if (col > rg + lg * 4 + r) sc[g][s][r] = -INFINITY;
                    }
                    float al[4];
#pragma unroll
                    for (int r = 0; r < 4; ++r) {
                        float mt = fmaxf(sc[g][0][r], sc[g][1][r]);
                        mt = fmaxf(mt, __shfl_xor(mt, 1));
                        mt = fmaxf(mt, __shfl_xor(mt, 2));
                        mt = fmaxf(mt, __shfl_xor(mt, 4));
                        mt = fmaxf(mt, __shfl_xor(mt, 8));
                        const float mn = fmaxf(m_r[g][r], mt);
                        al[r] = __expf(m_r[g][r] - mn);
                        m_r[g][r] = mn;
                    }
#pragma unroll
                    for (int s = 0; s < 2; ++s) {
#pragma unroll
                        for (int r = 0; r < 4; ++r) {
                            const float pv = __expf(sc[g][s][r] - m_r[g][r]);
                            sc[g][s][r] = pv;
                            Ps[w][g][lg * 4 + r][s * 16 + lr] = (__bf16)pv;
                        }
                    }
#pragma unroll
                    for (int r = 0; r < 4; ++r) {
                        float ls = sc[g][0][r] + sc[g][1][r];
                        ls += __shfl_xor(ls, 1);
                        ls += __shfl_xor(ls, 2);
                        ls += __shfl_xor(ls, 4);
                        ls += __shfl_xor(ls, 8);
                        l_r[g][r] = l_r[g][r] * al[r] + ls;
                    }
#pragma unroll
                    for (int n = 0; n < 8; ++n)
#pragma unroll
                        for (int r = 0; r < 4; ++r) O[g][n][r] *= al[r];
                }
                // ---- PV ----
                bf16x8 vf[8];
#pragma unroll
                for (int n = 0; n < 8; ++n)
                    vf[n] = *(const bf16x8*)&Vs[cur][n * 16 + lr][lg * 8];
#pragma unroll
                for (int g = 0; g < 2; ++g) {
                    const bool actg = (g == 0) ? act0 : act1;
                    if (!actg) continue;
                    const bf16x8 pf = *(const bf16x8*)&Ps[w][g][lr][lg * 8];
#pragma unroll
                    for (int n = 0; n < 8; ++n)
                        O[g][n] = __builtin_amdgcn_mfma_f32_16x16x32_bf16(pf, vf[n], O[g][n], 0, 0, 0);
                }
            }

            if (hasNext) stage_write(cur ^ 1);       // vmcnt wait inserted by compiler
            __syncthreads();
            cur ^= 1;
        }

        // ---- epilogue for this part ----
#pragma unroll
        for (int g = 0; g < 2; ++g) {
            float inv[4];
#pragma unroll
            for (int r = 0; r < 4; ++r) inv[r] = 1.0f / l_r[g][r];
#pragma unroll
            for (int n = 0; n < 8; ++n) {
#pragma unroll
                for (int r = 0; r < 4; ++r) {
                    const size_t t = (size_t)(b * SS + rg0 + g * 16 + lg * 4 + r);
                    att[(t * NHH + h) * 128 + n * 16 + lr] = (__bf16)(O[g][n][r] * inv[r]);
                }
            }
        }
    }
}

// ---------------------------------------------------------------------------
extern "C" void kernel_launch(void* const* d_in, const int* in_sizes, int n_in,
                              void* d_out, int out_size, void* d_ws, size_t ws_size,
                              hipStream_t stream) {
    (void)in_sizes; (void)n_in; (void)out_size; (void)ws_size;
    const float* x        = (const float*)d_in[0];
    const float* wq_down  = (const float*)d_in[1];
    const float* wq_up    = (const float*)d_in[2];
    const float* wq_rope  = (const float*)d_in[3];
    const float* q_norm_w = (const float*)d_in[4];
    const float* wkv_down = (const float*)d_in[5];
    const float* kv_norm_w= (const float*)d_in[6];
    const float* wkv_up   = (const float*)d_in[7];
    const float* wk_rope  = (const float*)d_in[8];
    const float* wo       = (const float*)d_in[9];
    float* out = (float*)d_out;

    char* ws = (char*)d_ws;
    float*  q_c   = (float*)(ws + 0);            // 24MB fp32 [4096][1536]
    __bf16* att   = (__bf16*)(ws + 0);           // 16MB bf16, aliases dead q_c
    float*  kv_c  = (float*)(ws + 25165824);     // 8MB fp32 [4096][512]
    __bf16* xb    = (__bf16*)(ws + 33554432);    // 16MB bf16 [4096][2048]
    __bf16* vT    = (__bf16*)(ws + 33554432);    // 16MB bf16, aliases dead xb
    __bf16* qc_b  = (__bf16*)(ws + 50331648);    // 12MB bf16 [4096][1536]
    __bf16* kvc_b = (__bf16*)(ws + 62914560);    // 4MB bf16 [4096][512]
    __bf16* krope = (__bf16*)(ws + 67108864);    // 0.5MB bf16 [4096][64]
    __bf16* qbuf  = (__bf16*)(ws + 67633152);    // 24MB bf16 [4096][3072]
    __bf16* wqd_b = (__bf16*)(ws + 92798976);    // 6MB
    __bf16* wqu_b = (__bf16*)(ws + 99090432);    // 6MB
    __bf16* wqr_b = (__bf16*)(ws + 105381888);   // 3MB
    __bf16* wkvd_b= (__bf16*)(ws + 108527616);   // 2MB
    __bf16* wkvu_b= (__bf16*)(ws + 110624768);   // 4MB
    __bf16* wkr_b = (__bf16*)(ws + 114819072);   // 0.25MB
    __bf16* wo_b  = (__bf16*)(ws + 99090432);    // 8MB, aliases wqu_b+wqr_b (dead after gemmQ)
    __bf16* knope = (__bf16*)d_out;              // 16MB bf16 in d_out (dead until final GEMM)

    const dim3 blk(256);

    cast_f32_bf16<<<dim3(TT * 2048 / 2048), blk, 0, stream>>>(x, xb, TT * 2048);
    cast_f32_bf16<<<dim3(1536 * 2048 / 2048), blk, 0, stream>>>(wq_down, wqd_b, 1536 * 2048);
    cast_f32_bf16<<<dim3(512 * 2048 / 2048), blk, 0, stream>>>(wkv_down, wkvd_b, 512 * 2048);
    cast_f32_bf16<<<dim3(64 * 2048 / 2048), blk, 0, stream>>>(wk_rope, wkr_b, 64 * 2048);
    cast_f32_bf16<<<dim3(2048 * 1536 / 2048), blk, 0, stream>>>(wq_up, wqu_b, 2048 * 1536);
    cast_f32_bf16<<<dim3(1024 * 1536 / 2048), blk, 0, stream>>>(wq_rope, wqr_b, 1024 * 1536);
    cast_f32_bf16<<<dim3(4096 * 512 / 2048), blk, 0, stream>>>(wkv_up, wkvu_b, 4096 * 512);

    gemm_mfma<0><<<dim3(17, 32), blk, 0, stream>>>(xb, wqd_b, wkvd_b, wkr_b,
                                                   q_c, kv_c, krope, nullptr, TT, 2112, 2048);

    rmsnorm_k<<<dim3(TT), blk, 0, stream>>>(q_c, qc_b, q_norm_w, 1536);
    rmsnorm_k<<<dim3(TT), blk, 0, stream>>>(kv_c, kvc_b, kv_norm_w, 512);

    gemm_mfma<1><<<dim3(24, 32), blk, 0, stream>>>(qc_b, wqu_b, wqr_b, nullptr,
                                                   nullptr, nullptr, qbuf, nullptr, TT, 3072, 1536);

    cast_f32_bf16<<<dim3(2048 * 2048 / 2048), blk, 0, stream>>>(wo, wo_b, 2048 * 2048);

    gemm_mfma<2><<<dim3(32, 32), blk, 0, stream>>>(kvc_b, wkvu_b, nullptr, nullptr,
                                                   nullptr, nullptr, knope, vT, TT, 4096, 512);

    attn_mfma2<<<dim3(8, NHH, 2), blk, 0, stream>>>(qbuf, knope, krope, vT, att);

    gemm_mfma<3><<<dim3(16, 32), blk, 0, stream>>>(att, wo_b, nullptr, nullptr,
                                                   out, nullptr, nullptr, nullptr, TT, 2048, 2048);
}

// Round 5
// 385.531 us; speedup vs baseline: 12.9586x; 1.3343x over previous
//
#include <hip/hip_runtime.h>
#include <hip/hip_bf16.h>
#include <math.h>

#define NHH 16
#define SS  2048
#define TT  4096            // B*S tokens
#define DQK 192
#define QSCALE 0.07216878364870322f   // 1/sqrt(192)
#define ROPE_C 0.28782313662425574f   // 2*ln(10000)/64

typedef __bf16 bf16x8 __attribute__((ext_vector_type(8)));
typedef float f32x4 __attribute__((ext_vector_type(4)));

#define GLOAD16(gp, lp) __builtin_amdgcn_global_load_lds( \
    (const __attribute__((address_space(1))) void*)(gp),  \
    (__attribute__((address_space(3))) void*)(lp), 16, 0, 0)

// ---------------------------------------------------------------------------
// Fused fp32 -> bf16 cast of x + 6 weight tensors (compile-time segments).
// ---------------------------------------------------------------------------
#define SEG0 8388608     // x
#define SEG1 11534336    // + wq_down (3145728)
#define SEG2 12582912    // + wkv_down (1048576)
#define SEG3 12713984    // + wk_rope (131072)
#define SEG4 15859712    // + wq_up (3145728)
#define SEG5 17432576    // + wq_rope (1572864)
#define SEG6 19529728    // + wkv_up (2097152)

__global__ __launch_bounds__(256) void cast_all(
        const float* __restrict__ x, const float* __restrict__ wqd,
        const float* __restrict__ wkvd, const float* __restrict__ wkr,
        const float* __restrict__ wqu, const float* __restrict__ wqr,
        const float* __restrict__ wkvu,
        __bf16* __restrict__ xb, __bf16* __restrict__ wqd_b,
        __bf16* __restrict__ wkvd_b, __bf16* __restrict__ wkr_b,
        __bf16* __restrict__ wqu_b, __bf16* __restrict__ wqr_b,
        __bf16* __restrict__ wkvu_b) {
    const int i = (blockIdx.x * 256 + threadIdx.x) * 8;
    const float* src;
    __bf16* dst;
    int off;
    if (i < SEG0)      { src = x;    dst = xb;     off = i; }
    else if (i < SEG1) { src = wqd;  dst = wqd_b;  off = i - SEG0; }
    else if (i < SEG2) { src = wkvd; dst = wkvd_b; off = i - SEG1; }
    else if (i < SEG3) { src = wkr;  dst = wkr_b;  off = i - SEG2; }
    else if (i < SEG4) { src = wqu;  dst = wqu_b;  off = i - SEG3; }
    else if (i < SEG5) { src = wqr;  dst = wqr_b;  off = i - SEG4; }
    else               { src = wkvu; dst = wkvu_b; off = i - SEG5; }
    const float4 a = *(const float4*)(src + off);
    const float4 b = *(const float4*)(src + off + 4);
    __bf16 o[8] = {(__bf16)a.x, (__bf16)a.y, (__bf16)a.z, (__bf16)a.w,
                   (__bf16)b.x, (__bf16)b.y, (__bf16)b.z, (__bf16)b.w};
    *(bf16x8*)(dst + off) = *(const bf16x8*)o;
}

__global__ __launch_bounds__(256) void cast_f32_bf16(const float* __restrict__ in,
                                                     __bf16* __restrict__ out, int n) {
    const int i = (blockIdx.x * 256 + threadIdx.x) * 8;
    const float4 a = *(const float4*)(in + i);
    const float4 b = *(const float4*)(in + i + 4);
    __bf16 o[8] = {(__bf16)a.x, (__bf16)a.y, (__bf16)a.z, (__bf16)a.w,
                   (__bf16)b.x, (__bf16)b.y, (__bf16)b.z, (__bf16)b.w};
    *(bf16x8*)(out + i) = *(const bf16x8*)o;
}

// ---------------------------------------------------------------------------
// RMSNorm: fp32 in -> bf16 out
// ---------------------------------------------------------------------------
__global__ __launch_bounds__(256) void rmsnorm_k(const float* __restrict__ in,
                                                 __bf16* __restrict__ out,
                                                 const float* __restrict__ w, int N) {
    const int row = blockIdx.x;
    const float* xr = in + (size_t)row * N;
    float ss = 0.f;
    for (int i = threadIdx.x; i < N; i += 256) {
        float v = xr[i];
        ss += v * v;
    }
    __shared__ float red[256];
    red[threadIdx.x] = ss;
    __syncthreads();
    for (int s = 128; s > 0; s >>= 1) {
        if (threadIdx.x < s) red[threadIdx.x] += red[threadIdx.x + s];
        __syncthreads();
    }
    const float scale = rsqrtf(red[0] / (float)N + 1e-6f);
    __bf16* orow = out + (size_t)row * N;
    for (int i = threadIdx.x; i < N; i += 256) orow[i] = (__bf16)(xr[i] * scale * w[i]);
}

// ---------------------------------------------------------------------------
// bf16 MFMA NT-GEMM (m97 structure), same as round 4.
// ---------------------------------------------------------------------------
template<int MODE>
__global__ __launch_bounds__(256) void gemm_mfma(
        const __bf16* __restrict__ A,
        const __bf16* __restrict__ W0, const __bf16* __restrict__ W1,
        const __bf16* __restrict__ W2,
        float* __restrict__ F0, float* __restrict__ F1,
        __bf16* __restrict__ B0, __bf16* __restrict__ B1,
        int M, int N, int K) {
    __shared__ __bf16 As[128 * 32];
    __shared__ __bf16 Bs[128 * 32];
    const int tid = threadIdx.x;
    const int w = tid >> 6, l = tid & 63;
    const int lr = l & 15, lg = l >> 4;
    const int wr = w >> 1, wc = w & 1;
    const int m0 = blockIdx.y * 128;
    const int n0 = blockIdx.x * 128;

    const int sr = l >> 2;
    const int sc = (l & 3) * 8;
    const __bf16* ag[2];
    const __bf16* bg[2];
    __bf16* asd[2];
    __bf16* bsd[2];
#pragma unroll
    for (int c = 0; c < 2; ++c) {
        const int arow = m0 + w * 32 + c * 16 + sr;
        ag[c] = A + (size_t)arow * K + sc;
        const int n = n0 + w * 32 + c * 16 + sr;
        const __bf16* wp;
        if (MODE == 0) {
            if (n < 1536)      wp = W0 + (size_t)n * K;
            else if (n < 2048) wp = W1 + (size_t)(n - 1536) * K;
            else if (n < 2112) wp = W2 + (size_t)(n - 2048) * K;
            else               wp = W0;
        } else if (MODE == 1) {
            wp = (n < 2048) ? W0 + (size_t)n * K : W1 + (size_t)(n - 2048) * K;
        } else {
            wp = W0 + (size_t)n * K;
        }
        bg[c] = wp + sc;
        asd[c] = &As[(w * 32 + c * 16) * 32];
        bsd[c] = &Bs[(w * 32 + c * 16) * 32];
    }

    f32x4 acc[4][4];
#pragma unroll
    for (int i = 0; i < 4; ++i)
#pragma unroll
        for (int j = 0; j < 4; ++j) acc[i][j] = (f32x4){0.f, 0.f, 0.f, 0.f};

    for (int k0 = 0; k0 < K; k0 += 32) {
        GLOAD16(ag[0] + k0, asd[0]);
        GLOAD16(ag[1] + k0, asd[1]);
        GLOAD16(bg[0] + k0, bsd[0]);
        GLOAD16(bg[1] + k0, bsd[1]);
        __syncthreads();
        bf16x8 af[4], bfr[4];
#pragma unroll
        for (int i = 0; i < 4; ++i)
            af[i] = *(const bf16x8*)&As[(wr * 64 + i * 16 + lr) * 32 + lg * 8];
#pragma unroll
        for (int j = 0; j < 4; ++j)
            bfr[j] = *(const bf16x8*)&Bs[(wc * 64 + j * 16 + lr) * 32 + lg * 8];
#pragma unroll
        for (int i = 0; i < 4; ++i)
#pragma unroll
            for (int j = 0; j < 4; ++j)
                acc[i][j] = __builtin_amdgcn_mfma_f32_16x16x32_bf16(af[i], bfr[j], acc[i][j], 0, 0, 0);
        __syncthreads();
    }

#pragma unroll
    for (int i = 0; i < 4; ++i) {
#pragma unroll
        for (int j = 0; j < 4; ++j) {
#pragma unroll
            for (int r = 0; r < 4; ++r) {
                const int m = m0 + wr * 64 + i * 16 + lg * 4 + r;
                const int n = n0 + wc * 64 + j * 16 + lr;
                const float v = acc[i][j][r];
                float vp = 0.f;
                if (MODE == 0 || MODE == 1) vp = __shfl_xor(v, 1);
                if (MODE == 0) {
                    if (n < 1536) {
                        F0[(size_t)m * 1536 + n] = v;
                    } else if (n < 2048) {
                        F1[(size_t)m * 512 + (n - 1536)] = v;
                    } else if (n < 2112) {
                        const int jj = n - 2048;
                        const int fi = jj >> 1;
                        const int spos = m & (SS - 1);
                        const float freq = __expf(-ROPE_C * (float)fi);
                        const float ang = (float)spos * freq;
                        const float sn = __sinf(ang), cs = __cosf(ang);
                        const float o = (jj & 1) ? (vp * sn + v * cs) : (v * cs - vp * sn);
                        B0[(size_t)m * 64 + jj] = (__bf16)o;
                    }
                } else if (MODE == 1) {
                    if (n < 2048) {
                        B0[(size_t)m * 3072 + (n >> 7) * 192 + (n & 127)] = (__bf16)(v * QSCALE);
                    } else {
                        const int jj = n - 2048;
                        const int h = jj >> 6, dd = jj & 63;
                        const int fi = dd >> 1;
                        const int spos = m & (SS - 1);
                        const float freq = __expf(-ROPE_C * (float)fi);
                        const float ang = (float)spos * freq;
                        const float sn = __sinf(ang), cs = __cosf(ang);
                        const float o = (dd & 1) ? (vp * sn + v * cs) : (v * cs - vp * sn);
                        B0[(size_t)m * 3072 + h * 192 + 128 + dd] = (__bf16)(o * QSCALE);
                    }
                } else if (MODE == 2) {
                    const int h = n >> 8, off = n & 255;
                    if (off < 128)
                        B0[(size_t)m * 2048 + h * 128 + off] = (__bf16)v;
                    else
                        B1[(((size_t)(m >> 11) * NHH + h) * 128 + (off - 128)) * SS + (m & (SS - 1))] = (__bf16)v;
                } else {
                    F0[(size_t)m * N + n] = v;
                }
            }
        }
    }
}

// ---------------------------------------------------------------------------
// MFMA flash attention v3: 8 waves (512 thr), KV tile 64, double-buffered LDS
// shared by all waves, async reg-staging, causal tile-pairing, XCD swizzle,
// setprio around MFMA, defer-max.
// Flat grid 256 blocks: flat -> xcd=flat%8, rest=flat/8, bx=rest%8,
// g=xcd+8*(rest/8), h=g%16, b=g/16.  Block q-tiles {bx,15-bx} x 128 rows;
// wave w owns rows [w*16, w*16+16).
// ---------------------------------------------------------------------------
__global__ __launch_bounds__(512, 1) void attn_mfma3(
        const __bf16* __restrict__ q, const __bf16* __restrict__ knope,
        const __bf16* __restrict__ krope, const __bf16* __restrict__ vT,
        __bf16* __restrict__ att) {
    const int flat = blockIdx.x;
    const int xcd = flat & 7;
    const int rest = flat >> 3;
    const int bx = rest & 7;
    const int g8 = xcd + 8 * (rest >> 3);
    const int h = g8 & 15;
    const int b = g8 >> 4;

    const int tid = threadIdx.x;
    const int w  = tid >> 6;
    const int l  = tid & 63;
    const int lr = l & 15;
    const int lg = l >> 4;

    __shared__ __bf16 Ks[2][64][200];   // [kv][d], pitch 200
    __shared__ __bf16 Vs[2][128][72];   // [d][kv], pitch 72
    __shared__ __bf16 Ps[8][16][72];    // per-wave P, [qrow][kv]

    const int tiles[2] = {bx, 15 - bx};

    // staging: 2560 16B-chunks = 5 per thread. g<1536: K (64 rows x 24), else V (128 x 8)
    bf16x8 sreg[5];
    auto stage_load = [&](int kv0) {
#pragma unroll
        for (int i = 0; i < 5; ++i) {
            const int gc = tid + 512 * i;
            if (gc < 1536) {
                const int row = gc / 24, cc = gc - row * 24;
                const size_t t = (size_t)(b * SS + kv0 + row);
                const __bf16* src = (cc < 16)
                    ? knope + t * 2048 + h * 128 + cc * 8
                    : krope + t * 64 + (cc - 16) * 8;
                sreg[i] = *(const bf16x8*)src;
            } else {
                const int c = gc - 1536;
                const int row = c >> 3, cc = c & 7;
                sreg[i] = *(const bf16x8*)(vT + (((size_t)b * NHH + h) * 128 + row) * SS
                                              + kv0 + cc * 8);
            }
        }
    };
    auto stage_write = [&](int bi) {
#pragma unroll
        for (int i = 0; i < 5; ++i) {
            const int gc = tid + 512 * i;
            if (gc < 1536) {
                const int row = gc / 24, cc = gc - row * 24;
                *(bf16x8*)&Ks[bi][row][cc * 8] = sreg[i];
            } else {
                const int c = gc - 1536;
                *(bf16x8*)&Vs[bi][c >> 3][(c & 7) * 8] = sreg[i];
            }
        }
    };

    stage_load(0);
    stage_write(0);
    __syncthreads();
    int cur = 0;

#pragma unroll
    for (int p = 0; p < 2; ++p) {
        const int rg0 = tiles[p] * 128 + w * 16;
        const int nkt = 2 * tiles[p] + 2;

        bf16x8 qf[6];
        {
            const __bf16* qb = q + (((size_t)(b * SS + rg0 + lr)) * NHH + h) * DQK + lg * 8;
#pragma unroll
            for (int c = 0; c < 6; ++c) qf[c] = *(const bf16x8*)(qb + c * 32);
        }

        f32x4 O[8];
#pragma unroll
        for (int n = 0; n < 8; ++n) O[n] = (f32x4){0.f, 0.f, 0.f, 0.f};
        float m_r[4], l_r[4];
#pragma unroll
        for (int r = 0; r < 4; ++r) { m_r[r] = -INFINITY; l_r[r] = 0.f; }

        for (int kt = 0; kt < nkt; ++kt) {
            const int kv0 = kt * 64;
            const bool hasNext = (kt + 1 < nkt) || (p == 0);
            const int nxt = (kt + 1 < nkt) ? (kt + 1) * 64 : 0;
            if (hasNext) stage_load(nxt);

            if (kv0 <= rg0 + 15) {      // wave-level causal activity
                // ---- QK^T ----
                f32x4 sc[4];
#pragma unroll
                for (int s = 0; s < 4; ++s) {
                    if (kv0 + s * 16 <= rg0 + 15) {
                        bf16x8 kf[6];
#pragma unroll
                        for (int c = 0; c < 6; ++c)
                            kf[c] = *(const bf16x8*)&Ks[cur][s * 16 + lr][c * 32 + lg * 8];
                        f32x4 a = (f32x4){0.f, 0.f, 0.f, 0.f};
                        __builtin_amdgcn_s_setprio(1);
#pragma unroll
                        for (int c = 0; c < 6; ++c)
                            a = __builtin_amdgcn_mfma_f32_16x16x32_bf16(qf[c], kf[c], a, 0, 0, 0);
                        __builtin_amdgcn_s_setprio(0);
                        sc[s] = a;
                    } else {
                        sc[s] = (f32x4){-INFINITY, -INFINITY, -INFINITY, -INFINITY};
                    }
                }
                // ---- causal mask ----
#pragma unroll
                for (int s = 0; s < 4; ++s) {
                    const int col = kv0 + s * 16 + lr;
#pragma unroll
                    for (int r = 0; r < 4; ++r)
                        if (col > rg0 + lg * 4 + r) sc[s][r] = -INFINITY;
                }
                // ---- online softmax with defer-max ----
                float mt[4];
#pragma unroll
                for (int r = 0; r < 4; ++r) {
                    float m = fmaxf(fmaxf(sc[0][r], sc[1][r]), fmaxf(sc[2][r], sc[3][r]));
                    m = fmaxf(m, __shfl_xor(m, 1));
                    m = fmaxf(m, __shfl_xor(m, 2));
                    m = fmaxf(m, __shfl_xor(m, 4));
                    m = fmaxf(m, __shfl_xor(m, 8));
                    mt[r] = m;
                }
                const bool ok = (mt[0] <= m_r[0] + 8.f) && (mt[1] <= m_r[1] + 8.f) &&
                                (mt[2] <= m_r[2] + 8.f) && (mt[3] <= m_r[3] + 8.f);
                if (!__all(ok)) {
#pragma unroll
                    for (int r = 0; r < 4; ++r) {
                        const float mn = fmaxf(m_r[r], mt[r]);
                        const float al = __expf(m_r[r] - mn);
                        m_r[r] = mn;
                        l_r[r] *= al;
#pragma unroll
                        for (int n = 0; n < 8; ++n) O[n][r] *= al;
                    }
                }
#pragma unroll
                for (int s = 0; s < 4; ++s) {
#pragma unroll
                    for (int r = 0; r < 4; ++r) {
                        const float pv = __expf(sc[s][r] - m_r[r]);
                        sc[s][r] = pv;
                        Ps[w][lg * 4 + r][s * 16 + lr] = (__bf16)pv;
                    }
                }
#pragma unroll
                for (int r = 0; r < 4; ++r) {
                    float ls = (sc[0][r] + sc[1][r]) + (sc[2][r] + sc[3][r]);
                    ls += __shfl_xor(ls, 1);
                    ls += __shfl_xor(ls, 2);
                    ls += __shfl_xor(ls, 4);
                    ls += __shfl_xor(ls, 8);
                    l_r[r] += ls;
                }
                // ---- PV ----
                bf16x8 pf[2];
#pragma unroll
                for (int ks = 0; ks < 2; ++ks)
                    pf[ks] = *(const bf16x8*)&Ps[w][lr][ks * 32 + lg * 8];
#pragma unroll
                for (int n = 0; n < 8; ++n) {
                    bf16x8 v0 = *(const bf16x8*)&Vs[cur][n * 16 + lr][lg * 8];
                    bf16x8 v1 = *(const bf16x8*)&Vs[cur][n * 16 + lr][32 + lg * 8];
                    __builtin_amdgcn_s_setprio(1);
                    O[n] = __builtin_amdgcn_mfma_f32_16x16x32_bf16(pf[0], v0, O[n], 0, 0, 0);
                    O[n] = __builtin_amdgcn_mfma_f32_16x16x32_bf16(pf[1], v1, O[n], 0, 0, 0);
                    __builtin_amdgcn_s_setprio(0);
                }
            }

            if (hasNext) stage_write(cur ^ 1);
            __syncthreads();
            cur ^= 1;
        }

        // ---- epilogue ----
        float inv[4];
#pragma unroll
        for (int r = 0; r < 4; ++r) inv[r] = 1.0f / l_r[r];
#pragma unroll
        for (int n = 0; n < 8; ++n) {
#pragma unroll
            for (int r = 0; r < 4; ++r) {
                const size_t t = (size_t)(b * SS + rg0 + lg * 4 + r);
                att[(t * NHH + h) * 128 + n * 16 + lr] = (__bf16)(O[n][r] * inv[r]);
            }
        }
    }
}

// ---------------------------------------------------------------------------
extern "C" void kernel_launch(void* const* d_in, const int* in_sizes, int n_in,
                              void* d_out, int out_size, void* d_ws, size_t ws_size,
                              hipStream_t stream) {
    (void)in_sizes; (void)n_in; (void)out_size; (void)ws_size;
    const float* x        = (const float*)d_in[0];
    const float* wq_down  = (const float*)d_in[1];
    const float* wq_up    = (const float*)d_in[2];
    const float* wq_rope  = (const float*)d_in[3];
    const float* q_norm_w = (const float*)d_in[4];
    const float* wkv_down = (const float*)d_in[5];
    const float* kv_norm_w= (const float*)d_in[6];
    const float* wkv_up   = (const float*)d_in[7];
    const float* wk_rope  = (const float*)d_in[8];
    const float* wo       = (const float*)d_in[9];
    float* out = (float*)d_out;

    char* ws = (char*)d_ws;
    float*  q_c   = (float*)(ws + 0);            // 24MB fp32 [4096][1536]
    __bf16* att   = (__bf16*)(ws + 0);           // 16MB bf16, aliases dead q_c
    float*  kv_c  = (float*)(ws + 25165824);     // 8MB fp32 [4096][512]
    __bf16* xb    = (__bf16*)(ws + 33554432);    // 16MB bf16 [4096][2048]
    __bf16* vT    = (__bf16*)(ws + 33554432);    // 16MB bf16, aliases dead xb
    __bf16* qc_b  = (__bf16*)(ws + 50331648);    // 12MB bf16 [4096][1536]
    __bf16* kvc_b = (__bf16*)(ws + 62914560);    // 4MB bf16 [4096][512]
    __bf16* krope = (__bf16*)(ws + 67108864);    // 0.5MB bf16 [4096][64]
    __bf16* qbuf  = (__bf16*)(ws + 67633152);    // 24MB bf16 [4096][3072]
    __bf16* wqd_b = (__bf16*)(ws + 92798976);    // 6MB
    __bf16* wqu_b = (__bf16*)(ws + 99090432);    // 6MB
    __bf16* wqr_b = (__bf16*)(ws + 105381888);   // 3MB
    __bf16* wkvd_b= (__bf16*)(ws + 108527616);   // 2MB
    __bf16* wkvu_b= (__bf16*)(ws + 110624768);   // 4MB
    __bf16* wkr_b = (__bf16*)(ws + 114819072);   // 0.25MB
    __bf16* wo_b  = (__bf16*)(ws + 99090432);    // 8MB, aliases wqu_b+wqr_b (dead after gemmQ)
    __bf16* knope = (__bf16*)d_out;              // 16MB bf16 in d_out (dead until final GEMM)

    const dim3 blk(256);

    cast_all<<<dim3(SEG6 / 2048), blk, 0, stream>>>(
        x, wq_down, wkv_down, wk_rope, wq_up, wq_rope, wkv_up,
        xb, wqd_b, wkvd_b, wkr_b, wqu_b, wqr_b, wkvu_b);

    gemm_mfma<0><<<dim3(17, 32), blk, 0, stream>>>(xb, wqd_b, wkvd_b, wkr_b,
                                                   q_c, kv_c, krope, nullptr, TT, 2112, 2048);

    rmsnorm_k<<<dim3(TT), blk, 0, stream>>>(q_c, qc_b, q_norm_w, 1536);
    rmsnorm_k<<<dim3(TT), blk, 0, stream>>>(kv_c, kvc_b, kv_norm_w, 512);

    gemm_mfma<1><<<dim3(24, 32), blk, 0, stream>>>(qc_b, wqu_b, wqr_b, nullptr,
                                                   nullptr, nullptr, qbuf, nullptr, TT, 3072, 1536);

    cast_f32_bf16<<<dim3(2048 * 2048 / 2048), blk, 0, stream>>>(wo, wo_b, 2048 * 2048);

    gemm_mfma<2><<<dim3(32, 32), blk, 0, stream>>>(kvc_b, wkvu_b, nullptr, nullptr,
                                                   nullptr, nullptr, knope, vT, TT, 4096, 512);

    attn_mfma3<<<dim3(256), dim3(512), 0, stream>>>(qbuf, knope, krope, vT, att);

    gemm_mfma<3><<<dim3(16, 32), blk, 0, stream>>>(att, wo_b, nullptr, nullptr,
                                                   out, nullptr, nullptr, nullptr, TT, 2048, 2048);
}

// Round 6
// 370.613 us; speedup vs baseline: 13.4802x; 1.0403x over previous
//
#include <hip/hip_runtime.h>
#include <hip/hip_bf16.h>
#include <math.h>

#define NHH 16
#define SS  2048
#define TT  4096            // B*S tokens
#define DQK 192
#define QSCALE 0.07216878364870322f   // 1/sqrt(192)
#define ROPE_C 0.28782313662425574f   // 2*ln(10000)/64

typedef __bf16 bf16x8 __attribute__((ext_vector_type(8)));
typedef float f32x4 __attribute__((ext_vector_type(4)));

#define GLOAD16(gp, lp) __builtin_amdgcn_global_load_lds( \
    (const __attribute__((address_space(1))) void*)(gp),  \
    (__attribute__((address_space(3))) void*)(lp), 16, 0, 0)

// ---------------------------------------------------------------------------
// Fused fp32 -> bf16 cast of x + all 7 weight tensors.
// ---------------------------------------------------------------------------
#define SEG0 8388608     // x
#define SEG1 11534336    // + wq_down (3145728)
#define SEG2 12582912    // + wkv_down (1048576)
#define SEG3 12713984    // + wk_rope (131072)
#define SEG4 15859712    // + wq_up (3145728)
#define SEG5 17432576    // + wq_rope (1572864)
#define SEG6 19529728    // + wkv_up (2097152)
#define SEG7 23724032    // + wo (4194304)

__global__ __launch_bounds__(256) void cast_all(
        const float* __restrict__ x, const float* __restrict__ wqd,
        const float* __restrict__ wkvd, const float* __restrict__ wkr,
        const float* __restrict__ wqu, const float* __restrict__ wqr,
        const float* __restrict__ wkvu, const float* __restrict__ wo,
        __bf16* __restrict__ xb, __bf16* __restrict__ wqd_b,
        __bf16* __restrict__ wkvd_b, __bf16* __restrict__ wkr_b,
        __bf16* __restrict__ wqu_b, __bf16* __restrict__ wqr_b,
        __bf16* __restrict__ wkvu_b, __bf16* __restrict__ wo_b) {
    const int i = (blockIdx.x * 256 + threadIdx.x) * 8;
    const float* src;
    __bf16* dst;
    int off;
    if (i < SEG0)      { src = x;    dst = xb;     off = i; }
    else if (i < SEG1) { src = wqd;  dst = wqd_b;  off = i - SEG0; }
    else if (i < SEG2) { src = wkvd; dst = wkvd_b; off = i - SEG1; }
    else if (i < SEG3) { src = wkr;  dst = wkr_b;  off = i - SEG2; }
    else if (i < SEG4) { src = wqu;  dst = wqu_b;  off = i - SEG3; }
    else if (i < SEG5) { src = wqr;  dst = wqr_b;  off = i - SEG4; }
    else if (i < SEG6) { src = wkvu; dst = wkvu_b; off = i - SEG5; }
    else               { src = wo;   dst = wo_b;   off = i - SEG6; }
    const float4 a = *(const float4*)(src + off);
    const float4 b = *(const float4*)(src + off + 4);
    __bf16 o[8] = {(__bf16)a.x, (__bf16)a.y, (__bf16)a.z, (__bf16)a.w,
                   (__bf16)b.x, (__bf16)b.y, (__bf16)b.z, (__bf16)b.w};
    *(bf16x8*)(dst + off) = *(const bf16x8*)o;
}

// ---------------------------------------------------------------------------
// RMSNorm: fp32 in -> bf16 out
// ---------------------------------------------------------------------------
__global__ __launch_bounds__(256) void rmsnorm_k(const float* __restrict__ in,
                                                 __bf16* __restrict__ out,
                                                 const float* __restrict__ w, int N) {
    const int row = blockIdx.x;
    const float* xr = in + (size_t)row * N;
    float ss = 0.f;
    for (int i = threadIdx.x; i < N; i += 256) {
        float v = xr[i];
        ss += v * v;
    }
    __shared__ float red[256];
    red[threadIdx.x] = ss;
    __syncthreads();
    for (int s = 128; s > 0; s >>= 1) {
        if (threadIdx.x < s) red[threadIdx.x] += red[threadIdx.x + s];
        __syncthreads();
    }
    const float scale = rsqrtf(red[0] / (float)N + 1e-6f);
    __bf16* orow = out + (size_t)row * N;
    for (int i = threadIdx.x; i < N; i += 256) orow[i] = (__bf16)(xr[i] * scale * w[i]);
}

// ---------------------------------------------------------------------------
// bf16 MFMA NT-GEMM, 8-phase-style schedule (T2+T3+T4+T5):
//   BM=128, BN=256, BK=64, 512 thr (8 waves as 2x4), per-wave 64x64 output.
//   3-deep LDS pipeline (144KB), global_load_lds staging (2 issues/phase),
//   counted s_waitcnt vmcnt(6) once per K-tile (never 0 in steady state),
//   raw s_barrier (no drain), setprio(1) around MFMA clusters.
//   LDS XOR-swizzle col ^= ((row>>1)&7)<<3, applied to BOTH the global
//   staging source (inverse) and the ds_read address (m104/m231 rule).
// A: [M][K] bf16 row-major. Weights W*: [n][K] bf16 row-major.
// MODE epilogues identical to round 5.
// ---------------------------------------------------------------------------
template<int MODE>
__global__ __launch_bounds__(512, 1) void gemm8(
        const __bf16* __restrict__ A,
        const __bf16* __restrict__ W0, const __bf16* __restrict__ W1,
        const __bf16* __restrict__ W2,
        float* __restrict__ F0, float* __restrict__ F1,
        __bf16* __restrict__ B0, __bf16* __restrict__ B1,
        int M, int N, int K) {
    // 3 buffers x (A 128x64 + B 256x64) bf16 = 3 x 24576 elem = 147456 B
    __shared__ __bf16 lds[3 * 24576];
    const int tid = threadIdx.x;
    const int w = tid >> 6, l = tid & 63;
    const int lr = l & 15, lg = l >> 4;
    const int wm = w >> 2, wn = w & 3;
    const int m0 = blockIdx.y * 128;
    const int n0 = blockIdx.x * 256;

    // ---- staging geometry: lane covers (row = chunk*64 + srow, col c') ----
    const int srow = (w << 3) + (l >> 3);       // 0..63 within chunk
    const int scol = (l & 7) << 3;              // stored col (elems)
    const int sswz = ((srow >> 1) & 7) << 3;    // swizzle for this lane's row
    const int csw  = scol ^ sswz;               // logical col to fetch

    const __bf16* aptr[2];
#pragma unroll
    for (int a = 0; a < 2; ++a)
        aptr[a] = A + (size_t)(m0 + a * 64 + srow) * K + csw;

    const __bf16* bptr[4];
#pragma unroll
    for (int bb = 0; bb < 4; ++bb) {
        const int n = n0 + bb * 64 + srow;
        const __bf16* wp;
        if (MODE == 0) {
            if (n < 1536)      wp = W0 + (size_t)n * K;
            else if (n < 2048) wp = W1 + (size_t)(n - 1536) * K;
            else if (n < 2112) wp = W2 + (size_t)(n - 2048) * K;
            else               wp = W0;                     // clamp (masked at store)
        } else if (MODE == 1) {
            wp = (n < 2048) ? W0 + (size_t)n * K : W1 + (size_t)(n - 2048) * K;
        } else {
            wp = W0 + (size_t)n * K;
        }
        bptr[bb] = wp + csw;
    }

    auto stA = [&](int t2, int a) {
        GLOAD16(aptr[a] + (size_t)t2 * 64,
                &lds[(t2 % 3) * 24576 + a * 4096 + tid * 8]);
    };
    auto stB = [&](int t2, int b) {
        GLOAD16(bptr[b] + (size_t)t2 * 64,
                &lds[(t2 % 3) * 24576 + 8192 + b * 4096 + tid * 8]);
    };

    // ---- fragment read geometry ----
    const int rswz = ((lr >> 1) & 7) << 3;      // same swizzle fn: row bits 1-3

    f32x4 acc[4][4];
#pragma unroll
    for (int i = 0; i < 4; ++i)
#pragma unroll
        for (int j = 0; j < 4; ++j) acc[i][j] = (f32x4){0.f, 0.f, 0.f, 0.f};

    // prologue: stage tiles 0 and 1
    const int NT = K >> 6;
#pragma unroll
    for (int t = 0; t < 2; ++t) {
        stA(t, 0); stA(t, 1);
        stB(t, 0); stB(t, 1); stB(t, 2); stB(t, 3);
    }

    for (int t = 0; t < NT; ++t) {
        if (t + 1 < NT) asm volatile("s_waitcnt vmcnt(6)" ::: "memory");
        else            asm volatile("s_waitcnt vmcnt(0)" ::: "memory");
        __builtin_amdgcn_s_barrier();

        const __bf16* As_ = &lds[(t % 3) * 24576];
        const __bf16* Bs_ = As_ + 8192;
        const bool st = (t + 2 < NT);
        const int t2 = t + 2;

        bf16x8 fa[2][2], fb0[2][2], fb1[2][2];

        // ---- phase 0: read A-low + B-low, stage A(t+2), MFMA q(0,0) ----
#pragma unroll
        for (int i = 0; i < 2; ++i)
#pragma unroll
            for (int kk = 0; kk < 2; ++kk)
                fa[i][kk] = *(const bf16x8*)&As_[(wm * 64 + i * 16 + lr) * 64 +
                                                 ((kk * 32 + lg * 8) ^ rswz)];
#pragma unroll
        for (int j = 0; j < 2; ++j)
#pragma unroll
            for (int kk = 0; kk < 2; ++kk)
                fb0[j][kk] = *(const bf16x8*)&Bs_[(wn * 64 + j * 16 + lr) * 64 +
                                                  ((kk * 32 + lg * 8) ^ rswz)];
        if (st) { stA(t2, 0); stA(t2, 1); }
        __builtin_amdgcn_s_barrier();
        __builtin_amdgcn_s_setprio(1);
#pragma unroll
        for (int i = 0; i < 2; ++i)
#pragma unroll
            for (int j = 0; j < 2; ++j)
#pragma unroll
                for (int kk = 0; kk < 2; ++kk)
                    acc[i][j] = __builtin_amdgcn_mfma_f32_16x16x32_bf16(fa[i][kk], fb0[j][kk], acc[i][j], 0, 0, 0);
        __builtin_amdgcn_s_setprio(0);
        __builtin_amdgcn_s_barrier();

        // ---- phase 1: read B-high, stage B0/B1(t+2), MFMA q(0,1) ----
#pragma unroll
        for (int j = 0; j < 2; ++j)
#pragma unroll
            for (int kk = 0; kk < 2; ++kk)
                fb1[j][kk] = *(const bf16x8*)&Bs_[(wn * 64 + (j + 2) * 16 + lr) * 64 +
                                                  ((kk * 32 + lg * 8) ^ rswz)];
        if (st) { stB(t2, 0); stB(t2, 1); }
        __builtin_amdgcn_s_barrier();
        __builtin_amdgcn_s_setprio(1);
#pragma unroll
        for (int i = 0; i < 2; ++i)
#pragma unroll
            for (int j = 0; j < 2; ++j)
#pragma unroll
                for (int kk = 0; kk < 2; ++kk)
                    acc[i][j + 2] = __builtin_amdgcn_mfma_f32_16x16x32_bf16(fa[i][kk], fb1[j][kk], acc[i][j + 2], 0, 0, 0);
        __builtin_amdgcn_s_setprio(0);
        __builtin_amdgcn_s_barrier();

        // ---- phase 2: read A-high, stage B2/B3(t+2), MFMA q(1,1) ----
#pragma unroll
        for (int i = 0; i < 2; ++i)
#pragma unroll
            for (int kk = 0; kk < 2; ++kk)
                fa[i][kk] = *(const bf16x8*)&As_[(wm * 64 + (i + 2) * 16 + lr) * 64 +
                                                 ((kk * 32 + lg * 8) ^ rswz)];
        if (st) { stB(t2, 2); stB(t2, 3); }
        __builtin_amdgcn_s_barrier();
        __builtin_amdgcn_s_setprio(1);
#pragma unroll
        for (int i = 0; i < 2; ++i)
#pragma unroll
            for (int j = 0; j < 2; ++j)
#pragma unroll
                for (int kk = 0; kk < 2; ++kk)
                    acc[i + 2][j + 2] = __builtin_amdgcn_mfma_f32_16x16x32_bf16(fa[i][kk], fb1[j][kk], acc[i + 2][j + 2], 0, 0, 0);
        __builtin_amdgcn_s_setprio(0);
        __builtin_amdgcn_s_barrier();

        // ---- phase 3: MFMA q(1,0) (registers only) ----
        __builtin_amdgcn_s_setprio(1);
#pragma unroll
        for (int i = 0; i < 2; ++i)
#pragma unroll
            for (int j = 0; j < 2; ++j)
#pragma unroll
                for (int kk = 0; kk < 2; ++kk)
                    acc[i + 2][j] = __builtin_amdgcn_mfma_f32_16x16x32_bf16(fa[i][kk], fb0[j][kk], acc[i + 2][j], 0, 0, 0);
        __builtin_amdgcn_s_setprio(0);
        // next tile's start barrier doubles as this phase's end barrier
    }

    // ---- epilogue: m = m0 + wm*64 + i*16 + lg*4 + r, n = n0 + wn*64 + j*16 + lr
#pragma unroll
    for (int i = 0; i < 4; ++i) {
#pragma unroll
        for (int j = 0; j < 4; ++j) {
#pragma unroll
            for (int r = 0; r < 4; ++r) {
                const int m = m0 + wm * 64 + i * 16 + lg * 4 + r;
                const int n = n0 + wn * 64 + j * 16 + lr;
                const float v = acc[i][j][r];
                float vp = 0.f;
                if (MODE == 0 || MODE == 1) vp = __shfl_xor(v, 1);  // rope partner
                if (MODE == 0) {
                    if (n < 1536) {
                        F0[(size_t)m * 1536 + n] = v;
                    } else if (n < 2048) {
                        F1[(size_t)m * 512 + (n - 1536)] = v;
                    } else if (n < 2112) {
                        const int jj = n - 2048;
                        const int fi = jj >> 1;
                        const int spos = m & (SS - 1);
                        const float freq = __expf(-ROPE_C * (float)fi);
                        const float ang = (float)spos * freq;
                        const float sn = __sinf(ang), cs = __cosf(ang);
                        const float o = (jj & 1) ? (vp * sn + v * cs) : (v * cs - vp * sn);
                        B0[(size_t)m * 64 + jj] = (__bf16)o;
                    }
                } else if (MODE == 1) {
                    if (n < 2048) {
                        B0[(size_t)m * 3072 + (n >> 7) * 192 + (n & 127)] = (__bf16)(v * QSCALE);
                    } else {
                        const int jj = n - 2048;
                        const int h = jj >> 6, dd = jj & 63;
                        const int fi = dd >> 1;
                        const int spos = m & (SS - 1);
                        const float freq = __expf(-ROPE_C * (float)fi);
                        const float ang = (float)spos * freq;
                        const float sn = __sinf(ang), cs = __cosf(ang);
                        const float o = (dd & 1) ? (vp * sn + v * cs) : (v * cs - vp * sn);
                        B0[(size_t)m * 3072 + h * 192 + 128 + dd] = (__bf16)(o * QSCALE);
                    }
                } else if (MODE == 2) {
                    const int h = n >> 8, off = n & 255;
                    if (off < 128)
                        B0[(size_t)m * 2048 + h * 128 + off] = (__bf16)v;
                    else
                        B1[(((size_t)(m >> 11) * NHH + h) * 128 + (off - 128)) * SS + (m & (SS - 1))] = (__bf16)v;
                } else {
                    F0[(size_t)m * N + n] = v;
                }
            }
        }
    }
}

// ---------------------------------------------------------------------------
// MFMA flash attention v3 (unchanged from round 5).
// ---------------------------------------------------------------------------
__global__ __launch_bounds__(512, 1) void attn_mfma3(
        const __bf16* __restrict__ q, const __bf16* __restrict__ knope,
        const __bf16* __restrict__ krope, const __bf16* __restrict__ vT,
        __bf16* __restrict__ att) {
    const int flat = blockIdx.x;
    const int xcd = flat & 7;
    const int rest = flat >> 3;
    const int bx = rest & 7;
    const int g8 = xcd + 8 * (rest >> 3);
    const int h = g8 & 15;
    const int b = g8 >> 4;

    const int tid = threadIdx.x;
    const int w  = tid >> 6;
    const int l  = tid & 63;
    const int lr = l & 15;
    const int lg = l >> 4;

    __shared__ __bf16 Ks[2][64][200];
    __shared__ __bf16 Vs[2][128][72];
    __shared__ __bf16 Ps[8][16][72];

    const int tiles[2] = {bx, 15 - bx};

    bf16x8 sreg[5];
    auto stage_load = [&](int kv0) {
#pragma unroll
        for (int i = 0; i < 5; ++i) {
            const int gc = tid + 512 * i;
            if (gc < 1536) {
                const int row = gc / 24, cc = gc - row * 24;
                const size_t t = (size_t)(b * SS + kv0 + row);
                const __bf16* src = (cc < 16)
                    ? knope + t * 2048 + h * 128 + cc * 8
                    : krope + t * 64 + (cc - 16) * 8;
                sreg[i] = *(const bf16x8*)src;
            } else {
                const int c = gc - 1536;
                const int row = c >> 3, cc = c & 7;
                sreg[i] = *(const bf16x8*)(vT + (((size_t)b * NHH + h) * 128 + row) * SS
                                              + kv0 + cc * 8);
            }
        }
    };
    auto stage_write = [&](int bi) {
#pragma unroll
        for (int i = 0; i < 5; ++i) {
            const int gc = tid + 512 * i;
            if (gc < 1536) {
                const int row = gc / 24, cc = gc - row * 24;
                *(bf16x8*)&Ks[bi][row][cc * 8] = sreg[i];
            } else {
                const int c = gc - 1536;
                *(bf16x8*)&Vs[bi][c >> 3][(c & 7) * 8] = sreg[i];
            }
        }
    };

    stage_load(0);
    stage_write(0);
    __syncthreads();
    int cur = 0;

#pragma unroll
    for (int p = 0; p < 2; ++p) {
        const int rg0 = tiles[p] * 128 + w * 16;
        const int nkt = 2 * tiles[p] + 2;

        bf16x8 qf[6];
        {
            const __bf16* qb = q + (((size_t)(b * SS + rg0 + lr)) * NHH + h) * DQK + lg * 8;
#pragma unroll
            for (int c = 0; c < 6; ++c) qf[c] = *(const bf16x8*)(qb + c * 32);
        }

        f32x4 O[8];
#pragma unroll
        for (int n = 0; n < 8; ++n) O[n] = (f32x4){0.f, 0.f, 0.f, 0.f};
        float m_r[4], l_r[4];
#pragma unroll
        for (int r = 0; r < 4; ++r) { m_r[r] = -INFINITY; l_r[r] = 0.f; }

        for (int kt = 0; kt < nkt; ++kt) {
            const int kv0 = kt * 64;
            const bool hasNext = (kt + 1 < nkt) || (p == 0);
            const int nxt = (kt + 1 < nkt) ? (kt + 1) * 64 : 0;
            if (hasNext) stage_load(nxt);

            if (kv0 <= rg0 + 15) {
                f32x4 sc[4];
#pragma unroll
                for (int s = 0; s < 4; ++s) {
                    if (kv0 + s * 16 <= rg0 + 15) {
                        bf16x8 kf[6];
#pragma unroll
                        for (int c = 0; c < 6; ++c)
                            kf[c] = *(const bf16x8*)&Ks[cur][s * 16 + lr][c * 32 + lg * 8];
                        f32x4 a = (f32x4){0.f, 0.f, 0.f, 0.f};
                        __builtin_amdgcn_s_setprio(1);
#pragma unroll
                        for (int c = 0; c < 6; ++c)
                            a = __builtin_amdgcn_mfma_f32_16x16x32_bf16(qf[c], kf[c], a, 0, 0, 0);
                        __builtin_amdgcn_s_setprio(0);
                        sc[s] = a;
                    } else {
                        sc[s] = (f32x4){-INFINITY, -INFINITY, -INFINITY, -INFINITY};
                    }
                }
#pragma unroll
                for (int s = 0; s < 4; ++s) {
                    const int col = kv0 + s * 16 + lr;
#pragma unroll
                    for (int r = 0; r < 4; ++r)
                        if (col > rg0 + lg * 4 + r) sc[s][r] = -INFINITY;
                }
                float mt[4];
#pragma unroll
                for (int r = 0; r < 4; ++r) {
                    float m = fmaxf(fmaxf(sc[0][r], sc[1][r]), fmaxf(sc[2][r], sc[3][r]));
                    m = fmaxf(m, __shfl_xor(m, 1));
                    m = fmaxf(m, __shfl_xor(m, 2));
                    m = fmaxf(m, __shfl_xor(m, 4));
                    m = fmaxf(m, __shfl_xor(m, 8));
                    mt[r] = m;
                }
                const bool ok = (mt[0] <= m_r[0] + 8.f) && (mt[1] <= m_r[1] + 8.f) &&
                                (mt[2] <= m_r[2] + 8.f) && (mt[3] <= m_r[3] + 8.f);
                if (!__all(ok)) {
#pragma unroll
                    for (int r = 0; r < 4; ++r) {
                        const float mn = fmaxf(m_r[r], mt[r]);
                        const float al = __expf(m_r[r] - mn);
                        m_r[r] = mn;
                        l_r[r] *= al;
#pragma unroll
                        for (int n = 0; n < 8; ++n) O[n][r] *= al;
                    }
                }
#pragma unroll
                for (int s = 0; s < 4; ++s) {
#pragma unroll
                    for (int r = 0; r < 4; ++r) {
                        const float pv = __expf(sc[s][r] - m_r[r]);
                        sc[s][r] = pv;
                        Ps[w][lg * 4 + r][s * 16 + lr] = (__bf16)pv;
                    }
                }
#pragma unroll
                for (int r = 0; r < 4; ++r) {
                    float ls = (sc[0][r] + sc[1][r]) + (sc[2][r] + sc[3][r]);
                    ls += __shfl_xor(ls, 1);
                    ls += __shfl_xor(ls, 2);
                    ls += __shfl_xor(ls, 4);
                    ls += __shfl_xor(ls, 8);
                    l_r[r] += ls;
                }
                bf16x8 pf[2];
#pragma unroll
                for (int ks = 0; ks < 2; ++ks)
                    pf[ks] = *(const bf16x8*)&Ps[w][lr][ks * 32 + lg * 8];
#pragma unroll
                for (int n = 0; n < 8; ++n) {
                    bf16x8 v0 = *(const bf16x8*)&Vs[cur][n * 16 + lr][lg * 8];
                    bf16x8 v1 = *(const bf16x8*)&Vs[cur][n * 16 + lr][32 + lg * 8];
                    __builtin_amdgcn_s_setprio(1);
                    O[n] = __builtin_amdgcn_mfma_f32_16x16x32_bf16(pf[0], v0, O[n], 0, 0, 0);
                    O[n] = __builtin_amdgcn_mfma_f32_16x16x32_bf16(pf[1], v1, O[n], 0, 0, 0);
                    __builtin_amdgcn_s_setprio(0);
                }
            }

            if (hasNext) stage_write(cur ^ 1);
            __syncthreads();
            cur ^= 1;
        }

        float inv[4];
#pragma unroll
        for (int r = 0; r < 4; ++r) inv[r] = 1.0f / l_r[r];
#pragma unroll
        for (int n = 0; n < 8; ++n) {
#pragma unroll
            for (int r = 0; r < 4; ++r) {
                const size_t t = (size_t)(b * SS + rg0 + lg * 4 + r);
                att[(t * NHH + h) * 128 + n * 16 + lr] = (__bf16)(O[n][r] * inv[r]);
            }
        }
    }
}

// ---------------------------------------------------------------------------
extern "C" void kernel_launch(void* const* d_in, const int* in_sizes, int n_in,
                              void* d_out, int out_size, void* d_ws, size_t ws_size,
                              hipStream_t stream) {
    (void)in_sizes; (void)n_in; (void)out_size; (void)ws_size;
    const float* x        = (const float*)d_in[0];
    const float* wq_down  = (const float*)d_in[1];
    const float* wq_up    = (const float*)d_in[2];
    const float* wq_rope  = (const float*)d_in[3];
    const float* q_norm_w = (const float*)d_in[4];
    const float* wkv_down = (const float*)d_in[5];
    const float* kv_norm_w= (const float*)d_in[6];
    const float* wkv_up   = (const float*)d_in[7];
    const float* wk_rope  = (const float*)d_in[8];
    const float* wo       = (const float*)d_in[9];
    float* out = (float*)d_out;

    char* ws = (char*)d_ws;
    float*  q_c   = (float*)(ws + 0);            // 24MB fp32 [4096][1536]
    __bf16* att   = (__bf16*)(ws + 0);           // 16MB bf16, aliases dead q_c
    float*  kv_c  = (float*)(ws + 25165824);     // 8MB fp32 [4096][512]
    __bf16* xb    = (__bf16*)(ws + 33554432);    // 16MB bf16 [4096][2048]
    __bf16* vT    = (__bf16*)(ws + 33554432);    // 16MB bf16, aliases dead xb
    __bf16* qc_b  = (__bf16*)(ws + 50331648);    // 12MB bf16 [4096][1536]
    __bf16* kvc_b = (__bf16*)(ws + 62914560);    // 4MB bf16 [4096][512]
    __bf16* krope = (__bf16*)(ws + 67108864);    // 0.5MB bf16 [4096][64]
    __bf16* qbuf  = (__bf16*)(ws + 67633152);    // 24MB bf16 [4096][3072]
    __bf16* wqd_b = (__bf16*)(ws + 92798976);    // 6MB
    __bf16* wqu_b = (__bf16*)(ws + 99090432);    // 6MB
    __bf16* wqr_b = (__bf16*)(ws + 105381888);   // 3MB
    __bf16* wkvd_b= (__bf16*)(ws + 108527616);   // 2MB
    __bf16* wkvu_b= (__bf16*)(ws + 110624768);   // 4MB
    __bf16* wkr_b = (__bf16*)(ws + 114819072);   // 0.25MB
    __bf16* wo_b  = (__bf16*)(ws + 115081216);   // 8MB (end 123469824)
    __bf16* knope = (__bf16*)d_out;              // 16MB bf16 in d_out (dead until final GEMM)

    const dim3 blk(256);

    cast_all<<<dim3(SEG7 / 2048), blk, 0, stream>>>(
        x, wq_down, wkv_down, wk_rope, wq_up, wq_rope, wkv_up, wo,
        xb, wqd_b, wkvd_b, wkr_b, wqu_b, wqr_b, wkvu_b, wo_b);

    // X-GEMM: xb @ [wq_down | wkv_down | wk_rope]^T -> q_c, kv_c, krope(roped)
    gemm8<0><<<dim3(9, 32), dim3(512), 0, stream>>>(xb, wqd_b, wkvd_b, wkr_b,
                                                    q_c, kv_c, krope, nullptr, TT, 2112, 2048);

    rmsnorm_k<<<dim3(TT), blk, 0, stream>>>(q_c, qc_b, q_norm_w, 1536);
    rmsnorm_k<<<dim3(TT), blk, 0, stream>>>(kv_c, kvc_b, kv_norm_w, 512);

    // Q-GEMM: qc_b @ [wq_up | wq_rope]^T -> qbuf (scatter+rope+scale)
    gemm8<1><<<dim3(12, 32), dim3(512), 0, stream>>>(qc_b, wqu_b, wqr_b, nullptr,
                                                     nullptr, nullptr, qbuf, nullptr, TT, 3072, 1536);

    // KV-GEMM: kvc_b @ wkv_up^T -> knope, vT
    gemm8<2><<<dim3(16, 32), dim3(512), 0, stream>>>(kvc_b, wkvu_b, nullptr, nullptr,
                                                     nullptr, nullptr, knope, vT, TT, 4096, 512);

    attn_mfma3<<<dim3(256), dim3(512), 0, stream>>>(qbuf, knope, krope, vT, att);

    // O-GEMM: att @ wo^T -> out (fp32)
    gemm8<3><<<dim3(8, 32), dim3(512), 0, stream>>>(att, wo_b, nullptr, nullptr,
                                                    out, nullptr, nullptr, nullptr, TT, 2048, 2048);
}